// Round 3
// baseline (4508.978 us; speedup 1.0000x reference)
//
#include <hip/hip_runtime.h>
#include <stdint.h>

#define D_MODEL 768
#define NHEAD 4
#define DHEAD 192
#define SEQ 1024
#define NLAYER 12
#define NTOK 4096
#define NVOCAB 50257

typedef __attribute__((ext_vector_type(4))) float f32x4;
typedef __attribute__((ext_vector_type(4))) int i32x4;
typedef __attribute__((ext_vector_type(4))) unsigned short u16x4;

__device__ __forceinline__ unsigned short f2bf(float f) {
  unsigned u = __builtin_bit_cast(unsigned, f);
  u += 0x7FFFu + ((u >> 16) & 1u);
  return (unsigned short)(u >> 16);
}

// async global->LDS, 16B per lane; lds base must be wave-uniform
#define GLDS(src, dst)                                                   \
  __builtin_amdgcn_global_load_lds(                                      \
      (const __attribute__((address_space(1))) void*)(src),              \
      (__attribute__((address_space(3))) void*)(dst), 16, 0, 0)

// ---------------- embedding: h = tok_emb[x] + pos_emb ----------------
__global__ __launch_bounds__(256) void embed_kernel(
    const int* __restrict__ x, const float* __restrict__ tok,
    const float* __restrict__ pos, float* __restrict__ h) {
  int row = blockIdx.x;
  int t = row & (SEQ - 1);
  int id = x[row];
  const float* tp = tok + (long)id * D_MODEL;
  const float* pp = pos + (long)t * D_MODEL;
  float* hp = h + (long)row * D_MODEL;
  for (int j = threadIdx.x; j < D_MODEL; j += 256)
    hp[j] = tp[j] + pp[j];
}

// ---------------- layernorm (f32 in) -> bf16 out ----------------
__global__ __launch_bounds__(256) void ln_kernel(
    const float* __restrict__ h, const float* __restrict__ sc,
    const float* __restrict__ sh, unsigned short* __restrict__ out) {
  __shared__ float red[4];
  int row = blockIdx.x;
  const float* x = h + (long)row * D_MODEL;
  int tid = threadIdx.x;
  float v0 = x[tid], v1 = x[tid + 256], v2 = x[tid + 512];
  float s = v0 + v1 + v2;
  for (int o = 32; o > 0; o >>= 1) s += __shfl_xor(s, o);
  if ((tid & 63) == 0) red[tid >> 6] = s;
  __syncthreads();
  float mean = (red[0] + red[1] + red[2] + red[3]) * (1.0f / D_MODEL);
  __syncthreads();
  float d0 = v0 - mean, d1 = v1 - mean, d2 = v2 - mean;
  float q = d0 * d0 + d1 * d1 + d2 * d2;
  for (int o = 32; o > 0; o >>= 1) q += __shfl_xor(q, o);
  if ((tid & 63) == 0) red[tid >> 6] = q;
  __syncthreads();
  float var = (red[0] + red[1] + red[2] + red[3]) * (1.0f / D_MODEL);
  float r = rsqrtf(var + 1e-5f);
  unsigned short* op = out + (long)row * D_MODEL;
  op[tid]       = f2bf(d0 * r * sc[tid]       + sh[tid]);
  op[tid + 256] = f2bf(d1 * r * sc[tid + 256] + sh[tid + 256]);
  op[tid + 512] = f2bf(d2 * r * sc[tid + 512] + sh[tid + 512]);
}

// ---------------- weight transpose: f32 [K][N] -> bf16 [N][K] ----------------
__global__ __launch_bounds__(256) void wtrans_kernel(
    const float* __restrict__ w, unsigned short* __restrict__ wt, int K, int N) {
  __shared__ unsigned short tile[32][33];
  int n0 = blockIdx.x * 32, k0 = blockIdx.y * 32;
  int tx = threadIdx.x, ty = threadIdx.y;   // 32 x 8
  int n = n0 + tx; if (n >= N) n = N - 1;
  #pragma unroll
  for (int i = 0; i < 4; ++i) {
    int k = k0 + ty + i * 8;
    tile[ty + i * 8][tx] = f2bf(w[(long)k * N + n]);
  }
  __syncthreads();
  #pragma unroll
  for (int i = 0; i < 4; ++i) {
    int nn = n0 + ty + i * 8;
    if (nn < N)
      __builtin_nontemporal_store(tile[tx][ty + i * 8],
                                  &wt[(long)nn * K + k0 + tx]);
  }
}

// ---------------- V transpose: qkv bf16 -> vt[bh][DHEAD][SEQ] ----------------
__global__ __launch_bounds__(256) void vt_kernel(
    const unsigned short* __restrict__ qkv, unsigned short* __restrict__ vt) {
  __shared__ unsigned short tile[32][33];
  int bh = blockIdx.z, b = bh >> 2, hh = bh & 3;
  int t0 = blockIdx.x * 32, f0 = blockIdx.y * 32;
  int tx = threadIdx.x, ty = threadIdx.y;
  const unsigned short* src = qkv + (long)b * SEQ * 2304 + 2 * D_MODEL + hh * DHEAD;
  #pragma unroll
  for (int i = 0; i < 4; ++i) {
    int t = t0 + ty + i * 8;
    tile[ty + i * 8][tx] = src[(long)t * 2304 + f0 + tx];
  }
  __syncthreads();
  unsigned short* dst = vt + (long)bh * DHEAD * SEQ;
  #pragma unroll
  for (int i = 0; i < 4; ++i) {
    int f = f0 + ty + i * 8;
    __builtin_nontemporal_store(tile[tx][ty + i * 8],
                                &dst[(long)f * SEQ + t0 + tx]);
  }
}

// ------- causal row softmax, single pass: S f32 -> P bf16 (normalized) -------
__global__ __launch_bounds__(256) void softmax_kernel(
    const float* __restrict__ S, unsigned short* __restrict__ P) {
  __shared__ float red[4];
  long rid = blockIdx.x;            // bh*1024 + q
  int q = (int)(rid & (SEQ - 1));
  int tid = threadIdx.x;
  int i0 = tid * 4;
  f32x4 v = __builtin_nontemporal_load((const f32x4*)(S + rid * SEQ + i0));
  float m = -3.0e38f;
  #pragma unroll
  for (int j = 0; j < 4; ++j) {
    if (i0 + j > q) v[j] = -3.0e38f;
    m = fmaxf(m, v[j]);
  }
  for (int o = 32; o > 0; o >>= 1) m = fmaxf(m, __shfl_xor(m, o));
  if ((tid & 63) == 0) red[tid >> 6] = m;
  __syncthreads();
  m = fmaxf(fmaxf(red[0], red[1]), fmaxf(red[2], red[3]));
  __syncthreads();
  float e[4];
  float sum = 0.f;
  #pragma unroll
  for (int j = 0; j < 4; ++j) {
    e[j] = (i0 + j > q) ? 0.f : __expf(v[j] - m);
    sum += e[j];
  }
  for (int o = 32; o > 0; o >>= 1) sum += __shfl_xor(sum, o);
  if ((tid & 63) == 0) red[tid >> 6] = sum;
  __syncthreads();
  float inv = 1.0f / (red[0] + red[1] + red[2] + red[3]);
  u16x4 out;
  #pragma unroll
  for (int j = 0; j < 4; ++j) out[j] = f2bf(e[j] * inv);
  __builtin_nontemporal_store(out, (u16x4*)(P + rid * SEQ + i0));
}

// ---------------- GEMM: C = A[M][K](bf16) x Bt[N][K](bf16), epilogue by MODE ----
// MODE 0: bf16 = acc + bias        (QKV)
// MODE 1: bf16 = relu(acc + bias)  (FC)
// MODE 2: f32  = acc * alpha       (S scores)
// MODE 3: f32 += acc + bias        (PV -> h, PROJ -> h)
// MODE 4: f32  = acc + bias        (head)
// All pure-overwrite outputs use non-temporal stores (no write-allocate RFO).
// causal: 0 none, 1 skip upper-tri N-blocks (S), 2 limit K to m0+BM (PV)
// mblocks > 0: 1D grid, linear id = n_blk*mblocks + m_blk (m fastest),
//              XCD-chunked swizzle (gridDim.x % 8 == 0 required)
#define BM 128
#define BN 128
#define BKK 32

template<int MODE>
__global__ __launch_bounds__(256) void gemm_kernel(
    const unsigned short* __restrict__ A, int lda,
    const unsigned short* __restrict__ B, int ldb,
    const float* __restrict__ bias,
    void* __restrict__ Cv, int ldc,
    int M, int N, int K,
    int NI, long sAo, long sAi, long sBo, long sBi,
    long sCo, long sCi, float alpha, int causal, int mblocks) {
  __shared__ __align__(16) unsigned short As[BM * BKK];
  __shared__ __align__(16) unsigned short Bs[BN * BKK];
  int z = blockIdx.z;
  int zo = z / NI, zi = z - zo * NI;
  A += zo * sAo + zi * sAi;
  B += zo * sBo + zi * sBi;
  long coff = zo * sCo + zi * sCi;

  int m0, n0;
  if (mblocks > 0) {
    int bid = blockIdx.x;
    int qq = (int)gridDim.x >> 3;       // gridDim.x % 8 == 0
    bid = (bid & 7) * qq + (bid >> 3);  // XCD-chunked, bijective
    m0 = (bid % mblocks) * BM;
    n0 = (bid / mblocks) * BN;
  } else {
    m0 = blockIdx.y * BM;
    n0 = blockIdx.x * BN;
  }
  if (causal == 1 && n0 > m0 + BM - 1) return;
  int kmax = (causal == 2) ? min(K, m0 + BM) : K;

  int tid = threadIdx.x;
  int lane = tid & 63;
  int wave = tid >> 6;
  int wm = (wave >> 1) * 64;
  int wn = (wave & 1) * 64;

  f32x4 acc[4][4] = {};

  for (int k0 = 0; k0 < kmax; k0 += BKK) {
    __syncthreads();
    #pragma unroll
    for (int i = 0; i < 2; ++i) {
      int c0 = i * 256 + wave * 64;     // wave-uniform chunk base
      int cc = c0 + lane;               // 16B chunk id, 512 per buffer
      int row = cc >> 2;
      int ko = (cc & 3) << 3;
      GLDS(A + (long)(m0 + row) * lda + k0 + ko, As + c0 * 8);
      int rg = n0 + row; if (rg >= N) rg = N - 1;
      GLDS(B + (long)rg * ldb + k0 + ko, Bs + c0 * 8);
    }
    __syncthreads();
    int lr = lane & 15;
    int kg = (lane >> 4) << 3;
    i32x4 af[4], bf[4];
    #pragma unroll
    for (int mi = 0; mi < 4; ++mi)
      af[mi] = *(const i32x4*)(As + (wm + mi * 16 + lr) * BKK + kg);
    #pragma unroll
    for (int ni = 0; ni < 4; ++ni)
      bf[ni] = *(const i32x4*)(Bs + (wn + ni * 16 + lr) * BKK + kg);
    #pragma unroll
    for (int mi = 0; mi < 4; ++mi)
      #pragma unroll
      for (int ni = 0; ni < 4; ++ni)
        asm("v_mfma_f32_16x16x32_bf16 %0, %1, %2, %0"
            : "+v"(acc[mi][ni]) : "v"(af[mi]), "v"(bf[ni]));
  }

  int cr = (lane >> 4) << 2;
  int cn = lane & 15;
  #pragma unroll
  for (int mi = 0; mi < 4; ++mi) {
    #pragma unroll
    for (int ni = 0; ni < 4; ++ni) {
      int col = n0 + wn + ni * 16 + cn;
      if (col >= N) continue;
      float bv = (MODE == 2) ? 0.f : (bias ? bias[col] : 0.f);
      #pragma unroll
      for (int r = 0; r < 4; ++r) {
        long row = m0 + wm + mi * 16 + cr + r;
        float v = acc[mi][ni][r] * alpha + bv;
        long idx = coff + row * ldc + col;
        if (MODE == 0)
          __builtin_nontemporal_store(f2bf(v), &((unsigned short*)Cv)[idx]);
        else if (MODE == 1)
          __builtin_nontemporal_store(f2bf(fmaxf(v, 0.f)),
                                      &((unsigned short*)Cv)[idx]);
        else if (MODE == 2)
          __builtin_nontemporal_store(v, &((float*)Cv)[idx]);
        else if (MODE == 3)
          ((float*)Cv)[idx] += v;
        else
          __builtin_nontemporal_store(v, &((float*)Cv)[idx]);
      }
    }
  }
}

extern "C" void kernel_launch(void* const* d_in, const int* in_sizes, int n_in,
                              void* d_out, int out_size, void* d_ws, size_t ws_size,
                              hipStream_t stream) {
  const int*   x       = (const int*)  d_in[0];
  const float* tok_emb = (const float*)d_in[1];
  const float* pos_emb = (const float*)d_in[2];
  const float* ln1_s   = (const float*)d_in[3];
  const float* ln1_b   = (const float*)d_in[4];
  const float* qkv_w   = (const float*)d_in[5];
  const float* qkv_b   = (const float*)d_in[6];
  const float* ln2_s   = (const float*)d_in[7];
  const float* ln2_b   = (const float*)d_in[8];
  const float* fc_w    = (const float*)d_in[9];
  const float* fc_b    = (const float*)d_in[10];
  const float* proj_w  = (const float*)d_in[11];
  const float* proj_b  = (const float*)d_in[12];
  const float* lnf_s   = (const float*)d_in[13];
  const float* lnf_b   = (const float*)d_in[14];
  const float* head_w  = (const float*)d_in[15];
  const float* head_b  = (const float*)d_in[16];

  char* ws = (char*)d_ws;
  size_t off = 0;
  auto alloc = [&](size_t bytes) {
    char* p = ws + off;
    off += (bytes + 255) & ~(size_t)255;
    return p;
  };
  float*          h   = (float*)         alloc((size_t)NTOK * D_MODEL * 4);
  unsigned short* lnb = (unsigned short*)alloc((size_t)NTOK * D_MODEL * 2);
  unsigned short* qkv = (unsigned short*)alloc((size_t)NTOK * 2304 * 2);
  unsigned short* vt  = (unsigned short*)alloc((size_t)16 * DHEAD * SEQ * 2);
  unsigned short* mid = (unsigned short*)alloc((size_t)NTOK * 3072 * 2);
  float*          S   = (float*)         alloc((size_t)16 * SEQ * SEQ * 4);
  unsigned short* P   = (unsigned short*)alloc((size_t)16 * SEQ * SEQ * 2);
  unsigned short* wtq = (unsigned short*)alloc((size_t)2304 * 768 * 2);
  unsigned short* wtf = (unsigned short*)alloc((size_t)3072 * 768 * 2);
  unsigned short* wtp = (unsigned short*)alloc((size_t)768 * 3072 * 2);
  unsigned short* wth = (unsigned short*)alloc((size_t)50304 * 768 * 2);

  embed_kernel<<<NTOK, 256, 0, stream>>>(x, tok_emb, pos_emb, h);

  const float rscale = 0.07216878364870323f;  // 1/sqrt(192)

  for (int l = 0; l < NLAYER; ++l) {
    // ---- attention ----
    wtrans_kernel<<<dim3(72, 24), dim3(32, 8), 0, stream>>>(
        qkv_w + (long)l * 768 * 2304, wtq, 768, 2304);
    ln_kernel<<<NTOK, 256, 0, stream>>>(h, ln1_s + l * 768, ln1_b + l * 768, lnb);
    gemm_kernel<0><<<dim3(18, 32, 1), 256, 0, stream>>>(
        lnb, 768, wtq, 768, qkv_b + l * 2304, qkv, 2304,
        4096, 2304, 768, 1, 0, 0, 0, 0, 0, 0, 1.0f, 0, 0);
    vt_kernel<<<dim3(32, 6, 16), dim3(32, 8), 0, stream>>>(qkv, vt);
    // S = scale * Q K^T   (batched over 16 (b,h); skip upper-tri blocks)
    gemm_kernel<2><<<dim3(8, 8, 16), 256, 0, stream>>>(
        qkv, 2304, qkv + 768, 2304, nullptr, S, 1024,
        1024, 1024, 192, 4,
        (long)1024 * 2304, 192, (long)1024 * 2304, 192,
        (long)4 * 1024 * 1024, (long)1024 * 1024, rscale, 1, 0);
    softmax_kernel<<<16384, 256, 0, stream>>>(S, P);
    // h += P V   (k-limited by causality)
    gemm_kernel<3><<<dim3(2, 8, 16), 256, 0, stream>>>(
        P, 1024, vt, 1024, nullptr, h, 768,
        1024, 192, 1024, 4,
        (long)4 * 1024 * 1024, (long)1024 * 1024,
        (long)4 * 192 * 1024, (long)192 * 1024,
        (long)1024 * 768, 192, 1.0f, 2, 0);
    // ---- MLP ----
    wtrans_kernel<<<dim3(96, 24), dim3(32, 8), 0, stream>>>(
        fc_w + (long)l * 768 * 3072, wtf, 768, 3072);
    ln_kernel<<<NTOK, 256, 0, stream>>>(h, ln2_s + l * 768, ln2_b + l * 768, lnb);
    gemm_kernel<1><<<dim3(24, 32, 1), 256, 0, stream>>>(
        lnb, 768, wtf, 768, fc_b + l * 3072, mid, 3072,
        4096, 3072, 768, 1, 0, 0, 0, 0, 0, 0, 1.0f, 0, 0);
    wtrans_kernel<<<dim3(24, 96), dim3(32, 8), 0, stream>>>(
        proj_w + (long)l * 3072 * 768, wtp, 3072, 768);
    gemm_kernel<3><<<dim3(6, 32, 1), 256, 0, stream>>>(
        mid, 3072, wtp, 3072, proj_b + l * 768, h, 768,
        4096, 768, 3072, 1, 0, 0, 0, 0, 0, 0, 1.0f, 0, 0);
  }

  // ---- final LN + head ----
  wtrans_kernel<<<dim3(1571, 24), dim3(32, 8), 0, stream>>>(head_w, wth, 768, 50257);
  ln_kernel<<<NTOK, 256, 0, stream>>>(h, lnf_s, lnf_b, lnb);
  // 1D grid, M-fast + XCD-chunked swizzle: each XCD sweeps whole N-panels,
  // head weight fetched from HBM ~once instead of ~once per M-block.
  gemm_kernel<4><<<dim3(393 * 32, 1, 1), 256, 0, stream>>>(
      lnb, 768, wth, 768, head_b, (float*)d_out, 50257,
      4096, 50257, 768, 1, 0, 0, 0, 0, 0, 0, 1.0f, 0, 32);
}

// Round 4
// 3354.570 us; speedup vs baseline: 1.3441x; 1.3441x over previous
//
#include <hip/hip_runtime.h>
#include <stdint.h>

#define D_MODEL 768
#define NHEAD 4
#define DHEAD 192
#define SEQ 1024
#define NLAYER 12
#define NTOK 4096
#define NVOCAB 50257

typedef __attribute__((ext_vector_type(4))) float f32x4;
typedef __attribute__((ext_vector_type(4))) int i32x4;
typedef __attribute__((ext_vector_type(4))) unsigned short u16x4;

__device__ __forceinline__ unsigned short f2bf(float f) {
  unsigned u = __builtin_bit_cast(unsigned, f);
  u += 0x7FFFu + ((u >> 16) & 1u);
  return (unsigned short)(u >> 16);
}

// async global->LDS, 16B per lane; lds base must be wave-uniform
#define GLDS(src, dst)                                                   \
  __builtin_amdgcn_global_load_lds(                                      \
      (const __attribute__((address_space(1))) void*)(src),              \
      (__attribute__((address_space(3))) void*)(dst), 16, 0, 0)

// ---------------- embedding: h = tok_emb[x] + pos_emb ----------------
__global__ __launch_bounds__(256) void embed_kernel(
    const int* __restrict__ x, const float* __restrict__ tok,
    const float* __restrict__ pos, float* __restrict__ h) {
  int row = blockIdx.x;
  int t = row & (SEQ - 1);
  int id = x[row];
  const float* tp = tok + (long)id * D_MODEL;
  const float* pp = pos + (long)t * D_MODEL;
  float* hp = h + (long)row * D_MODEL;
  for (int j = threadIdx.x; j < D_MODEL; j += 256)
    hp[j] = tp[j] + pp[j];
}

// ---------------- layernorm (f32 in) -> bf16 out ----------------
__global__ __launch_bounds__(256) void ln_kernel(
    const float* __restrict__ h, const float* __restrict__ sc,
    const float* __restrict__ sh, unsigned short* __restrict__ out) {
  __shared__ float red[4];
  int row = blockIdx.x;
  const float* x = h + (long)row * D_MODEL;
  int tid = threadIdx.x;
  float v0 = x[tid], v1 = x[tid + 256], v2 = x[tid + 512];
  float s = v0 + v1 + v2;
  for (int o = 32; o > 0; o >>= 1) s += __shfl_xor(s, o);
  if ((tid & 63) == 0) red[tid >> 6] = s;
  __syncthreads();
  float mean = (red[0] + red[1] + red[2] + red[3]) * (1.0f / D_MODEL);
  __syncthreads();
  float d0 = v0 - mean, d1 = v1 - mean, d2 = v2 - mean;
  float q = d0 * d0 + d1 * d1 + d2 * d2;
  for (int o = 32; o > 0; o >>= 1) q += __shfl_xor(q, o);
  if ((tid & 63) == 0) red[tid >> 6] = q;
  __syncthreads();
  float var = (red[0] + red[1] + red[2] + red[3]) * (1.0f / D_MODEL);
  float r = rsqrtf(var + 1e-5f);
  unsigned short* op = out + (long)row * D_MODEL;
  op[tid]       = f2bf(d0 * r * sc[tid]       + sh[tid]);
  op[tid + 256] = f2bf(d1 * r * sc[tid + 256] + sh[tid + 256]);
  op[tid + 512] = f2bf(d2 * r * sc[tid + 512] + sh[tid + 512]);
}

// ------- fused per-layer weight transpose: 3 weights, one launch -------
// f32 [K][N] -> bf16 [N][K]; all dims multiples of 32, no bounds checks.
__global__ __launch_bounds__(256) void wtrans3_kernel(
    const float* __restrict__ qw, const float* __restrict__ fw,
    const float* __restrict__ pw, unsigned short* __restrict__ tq,
    unsigned short* __restrict__ tf, unsigned short* __restrict__ tp) {
  __shared__ unsigned short tile[32][33];
  int bid = blockIdx.x;
  const float* src; unsigned short* dst; int K, N, nb;
  if (bid < 1728)               { src = qw; dst = tq; K = 768;  N = 2304; nb = 72; }
  else if ((bid -= 1728) < 2304){ src = fw; dst = tf; K = 768;  N = 3072; nb = 96; }
  else { bid -= 2304;             src = pw; dst = tp; K = 3072; N = 768;  nb = 24; }
  int n0 = (bid % nb) * 32, k0 = (bid / nb) * 32;
  int tx = threadIdx.x & 31, ty = threadIdx.x >> 5;   // 32 x 8
  #pragma unroll
  for (int i = 0; i < 4; ++i) {
    int k = k0 + ty + i * 8;
    tile[ty + i * 8][tx] = f2bf(src[(long)k * N + n0 + tx]);
  }
  __syncthreads();
  #pragma unroll
  for (int i = 0; i < 4; ++i) {
    int nn = n0 + ty + i * 8;
    dst[(long)nn * K + k0 + tx] = tile[tx][ty + i * 8];
  }
}

// ---------------- head weight transpose (N tail) ----------------
__global__ __launch_bounds__(256) void wtrans_kernel(
    const float* __restrict__ w, unsigned short* __restrict__ wt, int K, int N) {
  __shared__ unsigned short tile[32][33];
  int n0 = blockIdx.x * 32, k0 = blockIdx.y * 32;
  int tx = threadIdx.x, ty = threadIdx.y;   // 32 x 8
  int n = n0 + tx; if (n >= N) n = N - 1;
  #pragma unroll
  for (int i = 0; i < 4; ++i) {
    int k = k0 + ty + i * 8;
    tile[ty + i * 8][tx] = f2bf(w[(long)k * N + n]);
  }
  __syncthreads();
  #pragma unroll
  for (int i = 0; i < 4; ++i) {
    int nn = n0 + ty + i * 8;
    if (nn < N) wt[(long)nn * K + k0 + tx] = tile[tx][ty + i * 8];
  }
}

// ---------------- V transpose: qkv bf16 -> vt[bh][DHEAD][SEQ] ----------------
__global__ __launch_bounds__(256) void vt_kernel(
    const unsigned short* __restrict__ qkv, unsigned short* __restrict__ vt) {
  __shared__ unsigned short tile[32][33];
  int bh = blockIdx.z, b = bh >> 2, hh = bh & 3;
  int t0 = blockIdx.x * 32, f0 = blockIdx.y * 32;
  int tx = threadIdx.x, ty = threadIdx.y;
  const unsigned short* src = qkv + (long)b * SEQ * 2304 + 2 * D_MODEL + hh * DHEAD;
  #pragma unroll
  for (int i = 0; i < 4; ++i) {
    int t = t0 + ty + i * 8;
    tile[ty + i * 8][tx] = src[(long)t * 2304 + f0 + tx];
  }
  __syncthreads();
  unsigned short* dst = vt + (long)bh * DHEAD * SEQ;
  #pragma unroll
  for (int i = 0; i < 4; ++i) {
    int f = f0 + ty + i * 8;
    dst[(long)f * SEQ + t0 + tx] = tile[tx][ty + i * 8];
  }
}

// ------- causal row softmax, single pass: S f32 -> P bf16 (normalized) -------
// Loads only unmasked vectors; writes P only for cols < roundup(q+1,128)
// (PV's K-loop never reads beyond that).
__global__ __launch_bounds__(256) void softmax_kernel(
    const float* __restrict__ S, unsigned short* __restrict__ P) {
  __shared__ float red[4];
  long rid = blockIdx.x;            // bh*1024 + q
  int q = (int)(rid & (SEQ - 1));
  int tid = threadIdx.x;
  int i0 = tid * 4;
  f32x4 v;
  if (i0 <= q) {
    v = *(const f32x4*)(S + rid * SEQ + i0);
  } else {
    v = f32x4{-3.0e38f, -3.0e38f, -3.0e38f, -3.0e38f};
  }
  float m = -3.0e38f;
  #pragma unroll
  for (int j = 0; j < 4; ++j) {
    if (i0 + j > q) v[j] = -3.0e38f;
    m = fmaxf(m, v[j]);
  }
  for (int o = 32; o > 0; o >>= 1) m = fmaxf(m, __shfl_xor(m, o));
  if ((tid & 63) == 0) red[tid >> 6] = m;
  __syncthreads();
  m = fmaxf(fmaxf(red[0], red[1]), fmaxf(red[2], red[3]));
  __syncthreads();
  float e[4];
  float sum = 0.f;
  #pragma unroll
  for (int j = 0; j < 4; ++j) {
    e[j] = (i0 + j > q) ? 0.f : __expf(v[j] - m);
    sum += e[j];
  }
  for (int o = 32; o > 0; o >>= 1) sum += __shfl_xor(sum, o);
  if ((tid & 63) == 0) red[tid >> 6] = sum;
  __syncthreads();
  float inv = 1.0f / (red[0] + red[1] + red[2] + red[3]);
  if ((i0 >> 7) <= (q >> 7)) {      // within written diagonal region
    u16x4 out;
    #pragma unroll
    for (int j = 0; j < 4; ++j) out[j] = f2bf(e[j] * inv);
    *(u16x4*)(P + rid * SEQ + i0) = out;
  }
}

// ---------------- GEMM: C = A[M][K](bf16) x Bt[N][K](bf16), epilogue by MODE ----
// MFMA called with operands SWAPPED (mfma(bf,af)) so each lane's 4 acc regs
// are 4 CONSECUTIVE output columns -> vectorized epilogue stores.
// MODE 0: bf16 = acc + bias        (QKV)
// MODE 1: bf16 = relu(acc + bias)  (FC)
// MODE 2: f32  = acc * alpha       (S scores)
// MODE 3: f32 += acc + bias        (PV -> h, PROJ -> h)
// MODE 4: f32  = acc + bias        (head)
// causal: 0 none, 1 skip upper-tri N-blocks (S), 2 limit K to m0+BM (PV)
// mblocks > 0: 1D grid, linear id = n_blk*mblocks + m_blk (m fastest),
//              XCD-chunked swizzle (gridDim.x % 8 == 0 required)
#define BM 128
#define BN 128
#define BKK 32

template<int MODE>
__global__ __launch_bounds__(256) void gemm_kernel(
    const unsigned short* __restrict__ A, int lda,
    const unsigned short* __restrict__ B, int ldb,
    const float* __restrict__ bias,
    void* __restrict__ Cv, int ldc,
    int M, int N, int K,
    int NI, long sAo, long sAi, long sBo, long sBi,
    long sCo, long sCi, float alpha, int causal, int mblocks) {
  __shared__ __align__(16) unsigned short As[BM * BKK];
  __shared__ __align__(16) unsigned short Bs[BN * BKK];
  int z = blockIdx.z;
  int zo = z / NI, zi = z - zo * NI;
  A += zo * sAo + zi * sAi;
  B += zo * sBo + zi * sBi;
  long coff = zo * sCo + zi * sCi;

  int m0, n0;
  if (mblocks > 0) {
    int bid = blockIdx.x;
    int qq = (int)gridDim.x >> 3;       // gridDim.x % 8 == 0
    bid = (bid & 7) * qq + (bid >> 3);  // XCD-chunked, bijective
    m0 = (bid % mblocks) * BM;
    n0 = (bid / mblocks) * BN;
  } else {
    m0 = blockIdx.y * BM;
    n0 = blockIdx.x * BN;
  }
  if (causal == 1 && n0 > m0 + BM - 1) return;
  int kmax = (causal == 2) ? min(K, m0 + BM) : K;

  int tid = threadIdx.x;
  int lane = tid & 63;
  int wave = tid >> 6;
  int wm = (wave >> 1) * 64;
  int wn = (wave & 1) * 64;

  f32x4 acc[4][4] = {};

  for (int k0 = 0; k0 < kmax; k0 += BKK) {
    __syncthreads();
    #pragma unroll
    for (int i = 0; i < 2; ++i) {
      int c0 = i * 256 + wave * 64;     // wave-uniform chunk base
      int cc = c0 + lane;               // 16B chunk id, 512 per buffer
      int row = cc >> 2;
      int ko = (cc & 3) << 3;
      GLDS(A + (long)(m0 + row) * lda + k0 + ko, As + c0 * 8);
      int rg = n0 + row; if (rg >= N) rg = N - 1;
      GLDS(B + (long)rg * ldb + k0 + ko, Bs + c0 * 8);
    }
    __syncthreads();
    int lr = lane & 15;
    int kg = (lane >> 4) << 3;
    i32x4 af[4], bf[4];
    #pragma unroll
    for (int mi = 0; mi < 4; ++mi)
      af[mi] = *(const i32x4*)(As + (wm + mi * 16 + lr) * BKK + kg);
    #pragma unroll
    for (int ni = 0; ni < 4; ++ni)
      bf[ni] = *(const i32x4*)(Bs + (wn + ni * 16 + lr) * BKK + kg);
    #pragma unroll
    for (int mi = 0; mi < 4; ++mi)
      #pragma unroll
      for (int ni = 0; ni < 4; ++ni)
        asm("v_mfma_f32_16x16x32_bf16 %0, %1, %2, %0"
            : "+v"(acc[mi][ni]) : "v"(bf[ni]), "v"(af[mi]));  // SWAPPED
  }

  // Swapped-operand fragment: lane holds row = ..+ (lane&15),
  // cols = ..+ (lane>>4)*4 + r  (4 consecutive).
  int cm = lane & 15;
  int cg = (lane >> 4) << 2;
  #pragma unroll
  for (int mi = 0; mi < 4; ++mi) {
    long row = m0 + wm + mi * 16 + cm;
    #pragma unroll
    for (int ni = 0; ni < 4; ++ni) {
      int col = n0 + wn + ni * 16 + cg;
      f32x4 v = acc[mi][ni];
      if (MODE == 2) {                       // N multiple of 128, no tail
        #pragma unroll
        for (int r = 0; r < 4; ++r) v[r] *= alpha;
        *(f32x4*)((float*)Cv + coff + row * (long)ldc + col) = v;
      } else if (MODE == 0 || MODE == 1) {   // N multiple of 128, no tail
        f32x4 bv = *(const f32x4*)(bias + col);
        u16x4 o;
        #pragma unroll
        for (int r = 0; r < 4; ++r) {
          float t = v[r] + bv[r];
          if (MODE == 1) t = fmaxf(t, 0.f);
          o[r] = f2bf(t);
        }
        *(u16x4*)((unsigned short*)Cv + coff + row * (long)ldc + col) = o;
      } else {                               // MODE 3 / 4, may have N tail
        float* cp = (float*)Cv + coff + row * (long)ldc + col;
        if (col + 4 <= N) {
          f32x4 bv = bias ? *(const f32x4*)(bias + col)
                          : f32x4{0.f, 0.f, 0.f, 0.f};
          if (MODE == 3) {
            f32x4 old = *(f32x4*)cp;
            #pragma unroll
            for (int r = 0; r < 4; ++r) old[r] += v[r] + bv[r];
            *(f32x4*)cp = old;
          } else {
            f32x4 o;
            #pragma unroll
            for (int r = 0; r < 4; ++r) o[r] = v[r] + bv[r];
            *(f32x4*)cp = o;
          }
        } else {
          #pragma unroll
          for (int r = 0; r < 4; ++r) {
            if (col + r < N) {
              float bvr = bias ? bias[col + r] : 0.f;
              if (MODE == 3) cp[r] += v[r] + bvr;
              else           cp[r] = v[r] + bvr;
            }
          }
        }
      }
    }
  }
}

extern "C" void kernel_launch(void* const* d_in, const int* in_sizes, int n_in,
                              void* d_out, int out_size, void* d_ws, size_t ws_size,
                              hipStream_t stream) {
  const int*   x       = (const int*)  d_in[0];
  const float* tok_emb = (const float*)d_in[1];
  const float* pos_emb = (const float*)d_in[2];
  const float* ln1_s   = (const float*)d_in[3];
  const float* ln1_b   = (const float*)d_in[4];
  const float* qkv_w   = (const float*)d_in[5];
  const float* qkv_b   = (const float*)d_in[6];
  const float* ln2_s   = (const float*)d_in[7];
  const float* ln2_b   = (const float*)d_in[8];
  const float* fc_w    = (const float*)d_in[9];
  const float* fc_b    = (const float*)d_in[10];
  const float* proj_w  = (const float*)d_in[11];
  const float* proj_b  = (const float*)d_in[12];
  const float* lnf_s   = (const float*)d_in[13];
  const float* lnf_b   = (const float*)d_in[14];
  const float* head_w  = (const float*)d_in[15];
  const float* head_b  = (const float*)d_in[16];

  char* ws = (char*)d_ws;
  size_t off = 0;
  auto alloc = [&](size_t bytes) {
    char* p = ws + off;
    off += (bytes + 255) & ~(size_t)255;
    return p;
  };
  float*          h   = (float*)         alloc((size_t)NTOK * D_MODEL * 4);
  unsigned short* lnb = (unsigned short*)alloc((size_t)NTOK * D_MODEL * 2);
  unsigned short* qkv = (unsigned short*)alloc((size_t)NTOK * 2304 * 2);
  unsigned short* vt  = (unsigned short*)alloc((size_t)16 * DHEAD * SEQ * 2);
  unsigned short* mid = (unsigned short*)alloc((size_t)NTOK * 3072 * 2);
  float*          S   = (float*)         alloc((size_t)16 * SEQ * SEQ * 4);
  unsigned short* P   = (unsigned short*)alloc((size_t)16 * SEQ * SEQ * 2);
  unsigned short* wtq = (unsigned short*)alloc((size_t)2304 * 768 * 2);
  unsigned short* wtf = (unsigned short*)alloc((size_t)3072 * 768 * 2);
  unsigned short* wtp = (unsigned short*)alloc((size_t)768 * 3072 * 2);
  unsigned short* wth = (unsigned short*)alloc((size_t)50304 * 768 * 2);

  embed_kernel<<<NTOK, 256, 0, stream>>>(x, tok_emb, pos_emb, h);

  const float rscale = 0.07216878364870323f;  // 1/sqrt(192)

  for (int l = 0; l < NLAYER; ++l) {
    // ---- all three weight transposes in one launch ----
    wtrans3_kernel<<<6336, 256, 0, stream>>>(
        qkv_w + (long)l * 768 * 2304, fc_w + (long)l * 768 * 3072,
        proj_w + (long)l * 3072 * 768, wtq, wtf, wtp);
    // ---- attention ----
    ln_kernel<<<NTOK, 256, 0, stream>>>(h, ln1_s + l * 768, ln1_b + l * 768, lnb);
    gemm_kernel<0><<<dim3(18, 32, 1), 256, 0, stream>>>(
        lnb, 768, wtq, 768, qkv_b + l * 2304, qkv, 2304,
        4096, 2304, 768, 1, 0, 0, 0, 0, 0, 0, 1.0f, 0, 0);
    vt_kernel<<<dim3(32, 6, 16), dim3(32, 8), 0, stream>>>(qkv, vt);
    // S = scale * Q K^T   (batched over 16 (b,h); skip upper-tri blocks)
    gemm_kernel<2><<<dim3(8, 8, 16), 256, 0, stream>>>(
        qkv, 2304, qkv + 768, 2304, nullptr, S, 1024,
        1024, 1024, 192, 4,
        (long)1024 * 2304, 192, (long)1024 * 2304, 192,
        (long)4 * 1024 * 1024, (long)1024 * 1024, rscale, 1, 0);
    softmax_kernel<<<16384, 256, 0, stream>>>(S, P);
    // h += P V   (k-limited by causality)
    gemm_kernel<3><<<dim3(2, 8, 16), 256, 0, stream>>>(
        P, 1024, vt, 1024, nullptr, h, 768,
        1024, 192, 1024, 4,
        (long)4 * 1024 * 1024, (long)1024 * 1024,
        (long)4 * 192 * 1024, (long)192 * 1024,
        (long)1024 * 768, 192, 1.0f, 2, 0);
    // ---- MLP ----
    ln_kernel<<<NTOK, 256, 0, stream>>>(h, ln2_s + l * 768, ln2_b + l * 768, lnb);
    gemm_kernel<1><<<dim3(24, 32, 1), 256, 0, stream>>>(
        lnb, 768, wtf, 768, fc_b + l * 3072, mid, 3072,
        4096, 3072, 768, 1, 0, 0, 0, 0, 0, 0, 1.0f, 0, 0);
    gemm_kernel<3><<<dim3(6, 32, 1), 256, 0, stream>>>(
        mid, 3072, wtp, 3072, proj_b + l * 768, h, 768,
        4096, 768, 3072, 1, 0, 0, 0, 0, 0, 0, 1.0f, 0, 0);
  }

  // ---- final LN + head ----
  wtrans_kernel<<<dim3(1571, 24), dim3(32, 8), 0, stream>>>(head_w, wth, 768, 50257);
  ln_kernel<<<NTOK, 256, 0, stream>>>(h, lnf_s, lnf_b, lnb);
  // 1D grid, M-fast + XCD-chunked swizzle: each XCD sweeps whole N-panels,
  // head weight fetched from HBM ~once instead of ~once per M-block.
  gemm_kernel<4><<<dim3(393 * 32, 1, 1), 256, 0, stream>>>(
      lnb, 768, wth, 768, head_b, (float*)d_out, 50257,
      4096, 50257, 768, 1, 0, 0, 0, 0, 0, 0, 1.0f, 0, 32);
}

// Round 5
// 3273.114 us; speedup vs baseline: 1.3776x; 1.0249x over previous
//
#include <hip/hip_runtime.h>
#include <stdint.h>

#define D_MODEL 768
#define NHEAD 4
#define DHEAD 192
#define SEQ 1024
#define NLAYER 12
#define NTOK 4096
#define NVOCAB 50257

typedef __attribute__((ext_vector_type(4))) float f32x4;
typedef __attribute__((ext_vector_type(4))) int i32x4;
typedef __attribute__((ext_vector_type(4))) unsigned short u16x4;

__device__ __forceinline__ unsigned short f2bf(float f) {
  unsigned u = __builtin_bit_cast(unsigned, f);
  u += 0x7FFFu + ((u >> 16) & 1u);
  return (unsigned short)(u >> 16);
}

// async global->LDS, 16B per lane; lds base must be wave-uniform
#define GLDS(src, dst)                                                   \
  __builtin_amdgcn_global_load_lds(                                      \
      (const __attribute__((address_space(1))) void*)(src),              \
      (__attribute__((address_space(3))) void*)(dst), 16, 0, 0)

// ---------------- embedding: h = tok_emb[x] + pos_emb ----------------
__global__ __launch_bounds__(256) void embed_kernel(
    const int* __restrict__ x, const float* __restrict__ tok,
    const float* __restrict__ pos, float* __restrict__ h) {
  int row = blockIdx.x;
  int t = row & (SEQ - 1);
  int id = x[row];
  const float* tp = tok + (long)id * D_MODEL;
  const float* pp = pos + (long)t * D_MODEL;
  float* hp = h + (long)row * D_MODEL;
  for (int j = threadIdx.x; j < D_MODEL; j += 256)
    hp[j] = tp[j] + pp[j];
}

// ---------------- layernorm (f32 in) -> bf16 out ----------------
__global__ __launch_bounds__(256) void ln_kernel(
    const float* __restrict__ h, const float* __restrict__ sc,
    const float* __restrict__ sh, unsigned short* __restrict__ out) {
  __shared__ float red[4];
  int row = blockIdx.x;
  const float* x = h + (long)row * D_MODEL;
  int tid = threadIdx.x;
  float v0 = x[tid], v1 = x[tid + 256], v2 = x[tid + 512];
  float s = v0 + v1 + v2;
  for (int o = 32; o > 0; o >>= 1) s += __shfl_xor(s, o);
  if ((tid & 63) == 0) red[tid >> 6] = s;
  __syncthreads();
  float mean = (red[0] + red[1] + red[2] + red[3]) * (1.0f / D_MODEL);
  __syncthreads();
  float d0 = v0 - mean, d1 = v1 - mean, d2 = v2 - mean;
  float q = d0 * d0 + d1 * d1 + d2 * d2;
  for (int o = 32; o > 0; o >>= 1) q += __shfl_xor(q, o);
  if ((tid & 63) == 0) red[tid >> 6] = q;
  __syncthreads();
  float var = (red[0] + red[1] + red[2] + red[3]) * (1.0f / D_MODEL);
  float r = rsqrtf(var + 1e-5f);
  unsigned short* op = out + (long)row * D_MODEL;
  op[tid]       = f2bf(d0 * r * sc[tid]       + sh[tid]);
  op[tid + 256] = f2bf(d1 * r * sc[tid + 256] + sh[tid + 256]);
  op[tid + 512] = f2bf(d2 * r * sc[tid + 512] + sh[tid + 512]);
}

// ------- fused per-layer weight transpose: 3 weights, one launch -------
__global__ __launch_bounds__(256) void wtrans3_kernel(
    const float* __restrict__ qw, const float* __restrict__ fw,
    const float* __restrict__ pw, unsigned short* __restrict__ tq,
    unsigned short* __restrict__ tf, unsigned short* __restrict__ tp) {
  __shared__ unsigned short tile[32][33];
  int bid = blockIdx.x;
  const float* src; unsigned short* dst; int K, N, nb;
  if (bid < 1728)               { src = qw; dst = tq; K = 768;  N = 2304; nb = 72; }
  else if ((bid -= 1728) < 2304){ src = fw; dst = tf; K = 768;  N = 3072; nb = 96; }
  else { bid -= 2304;             src = pw; dst = tp; K = 3072; N = 768;  nb = 24; }
  int n0 = (bid % nb) * 32, k0 = (bid / nb) * 32;
  int tx = threadIdx.x & 31, ty = threadIdx.x >> 5;   // 32 x 8
  #pragma unroll
  for (int i = 0; i < 4; ++i) {
    int k = k0 + ty + i * 8;
    tile[ty + i * 8][tx] = f2bf(src[(long)k * N + n0 + tx]);
  }
  __syncthreads();
  #pragma unroll
  for (int i = 0; i < 4; ++i) {
    int nn = n0 + ty + i * 8;
    dst[(long)nn * K + k0 + tx] = tile[tx][ty + i * 8];
  }
}

// ---------------- head weight transpose (N tail) ----------------
__global__ __launch_bounds__(256) void wtrans_kernel(
    const float* __restrict__ w, unsigned short* __restrict__ wt, int K, int N) {
  __shared__ unsigned short tile[32][33];
  int n0 = blockIdx.x * 32, k0 = blockIdx.y * 32;
  int tx = threadIdx.x, ty = threadIdx.y;   // 32 x 8
  int n = n0 + tx; if (n >= N) n = N - 1;
  #pragma unroll
  for (int i = 0; i < 4; ++i) {
    int k = k0 + ty + i * 8;
    tile[ty + i * 8][tx] = f2bf(w[(long)k * N + n]);
  }
  __syncthreads();
  #pragma unroll
  for (int i = 0; i < 4; ++i) {
    int nn = n0 + ty + i * 8;
    if (nn < N) wt[(long)nn * K + k0 + tx] = tile[tx][ty + i * 8];
  }
}

// ---------------- V transpose: qkv bf16 -> vt[bh][DHEAD][SEQ] ----------------
__global__ __launch_bounds__(256) void vt_kernel(
    const unsigned short* __restrict__ qkv, unsigned short* __restrict__ vt) {
  __shared__ unsigned short tile[32][33];
  int bh = blockIdx.z, b = bh >> 2, hh = bh & 3;
  int t0 = blockIdx.x * 32, f0 = blockIdx.y * 32;
  int tx = threadIdx.x, ty = threadIdx.y;
  const unsigned short* src = qkv + (long)b * SEQ * 2304 + 2 * D_MODEL + hh * DHEAD;
  #pragma unroll
  for (int i = 0; i < 4; ++i) {
    int t = t0 + ty + i * 8;
    tile[ty + i * 8][tx] = src[(long)t * 2304 + f0 + tx];
  }
  __syncthreads();
  unsigned short* dst = vt + (long)bh * DHEAD * SEQ;
  #pragma unroll
  for (int i = 0; i < 4; ++i) {
    int f = f0 + ty + i * 8;
    dst[(long)f * SEQ + t0 + tx] = tile[tx][ty + i * 8];
  }
}

// ------- causal row softmax, single pass: S f32 -> P bf16 (normalized) -------
__global__ __launch_bounds__(256) void softmax_kernel(
    const float* __restrict__ S, unsigned short* __restrict__ P) {
  __shared__ float red[4];
  long rid = blockIdx.x;            // bh*1024 + q
  int q = (int)(rid & (SEQ - 1));
  int tid = threadIdx.x;
  int i0 = tid * 4;
  f32x4 v;
  if (i0 <= q) {
    v = *(const f32x4*)(S + rid * SEQ + i0);
  } else {
    v = f32x4{-3.0e38f, -3.0e38f, -3.0e38f, -3.0e38f};
  }
  float m = -3.0e38f;
  #pragma unroll
  for (int j = 0; j < 4; ++j) {
    if (i0 + j > q) v[j] = -3.0e38f;
    m = fmaxf(m, v[j]);
  }
  for (int o = 32; o > 0; o >>= 1) m = fmaxf(m, __shfl_xor(m, o));
  if ((tid & 63) == 0) red[tid >> 6] = m;
  __syncthreads();
  m = fmaxf(fmaxf(red[0], red[1]), fmaxf(red[2], red[3]));
  __syncthreads();
  float e[4];
  float sum = 0.f;
  #pragma unroll
  for (int j = 0; j < 4; ++j) {
    e[j] = (i0 + j > q) ? 0.f : __expf(v[j] - m);
    sum += e[j];
  }
  for (int o = 32; o > 0; o >>= 1) sum += __shfl_xor(sum, o);
  if ((tid & 63) == 0) red[tid >> 6] = sum;
  __syncthreads();
  float inv = 1.0f / (red[0] + red[1] + red[2] + red[3]);
  if ((i0 >> 7) <= (q >> 7)) {      // within written diagonal region
    u16x4 out;
    #pragma unroll
    for (int j = 0; j < 4; ++j) out[j] = f2bf(e[j] * inv);
    *(u16x4*)(P + rid * SEQ + i0) = out;
  }
}

// ---------------- GEMM: C = A[M][K](bf16) x Bt[N][K](bf16) ----------------
// Double-buffered 2-phase pipeline: stage tile t+1 (global_load_lds) BEFORE
// ds_read+MFMA of tile t; single vmcnt-draining barrier per K-step.
// MFMA operands swapped so each lane holds 4 consecutive output columns.
// MODE 0: bf16 = acc + bias        (QKV)
// MODE 1: bf16 = relu(acc + bias)  (FC)
// MODE 2: f32  = acc * alpha       (S scores)
// MODE 3: f32 += acc + bias        (PV -> h, PROJ -> h)
// MODE 4: f32  = acc + bias        (head)
// causal: 0 none, 1 skip upper-tri N-blocks (S), 2 limit K to m0+BM (PV)
// mblocks > 0: 1D grid, m-chunk-per-XCD swizzle (mblocks % 8 == 0):
//   xcd = bid&7 owns mblocks/8 M-blocks; N sweeps fastest within the chunk
//   so the A-panel stays L2-resident and B streams once per XCD (L3-shared).
#define BM 128
#define BN 128
#define BKK 32

template<int MODE>
__global__ __launch_bounds__(256) void gemm_kernel(
    const unsigned short* __restrict__ A, int lda,
    const unsigned short* __restrict__ B, int ldb,
    const float* __restrict__ bias,
    void* __restrict__ Cv, int ldc,
    int M, int N, int K,
    int NI, long sAo, long sAi, long sBo, long sBi,
    long sCo, long sCi, float alpha, int causal, int mblocks) {
  __shared__ __align__(16) unsigned short As[2][BM * BKK];
  __shared__ __align__(16) unsigned short Bs[2][BN * BKK];
  int z = blockIdx.z;
  int zo = z / NI, zi = z - zo * NI;
  A += zo * sAo + zi * sAi;
  B += zo * sBo + zi * sBi;
  long coff = zo * sCo + zi * sCi;

  int m0, n0;
  if (mblocks > 0) {
    int bid = blockIdx.x;
    int mpx = mblocks >> 3;             // m-blocks per XCD
    int xcd = bid & 7;
    int c = bid >> 3;                   // 0 .. mpx*nblocks-1
    m0 = (xcd * mpx + (c & (mpx - 1))) * BM;
    n0 = (c / mpx) * BN;
  } else {
    m0 = blockIdx.y * BM;
    n0 = blockIdx.x * BN;
  }
  if (causal == 1 && n0 > m0 + BM - 1) return;
  int kmax = (causal == 2) ? min(K, m0 + BM) : K;

  int tid = threadIdx.x;
  int lane = tid & 63;
  int wave = tid >> 6;
  int wm = (wave >> 1) * 64;
  int wn = (wave & 1) * 64;

  auto stage = [&](int buf, int k0) {
    #pragma unroll
    for (int i = 0; i < 2; ++i) {
      int c0 = i * 256 + wave * 64;     // wave-uniform chunk base
      int cc = c0 + lane;               // 16B chunk id, 512 per buffer
      int row = cc >> 2;
      int ko = (cc & 3) << 3;
      GLDS(A + (long)(m0 + row) * lda + k0 + ko, As[buf] + c0 * 8);
      int rg = n0 + row; if (rg >= N) rg = N - 1;
      GLDS(B + (long)rg * ldb + k0 + ko, Bs[buf] + c0 * 8);
    }
  };

  f32x4 acc[4][4] = {};
  int nt = kmax / BKK;                  // kmax always a multiple of 32 here
  stage(0, 0);
  __syncthreads();                      // drains vmcnt(0): buf0 ready
  int cur = 0;
  for (int t = 0; t < nt; ++t) {
    if (t + 1 < nt) stage(cur ^ 1, (t + 1) * BKK);   // prefetch next tile
    int lr = lane & 15;
    int kg = (lane >> 4) << 3;
    i32x4 af[4], bf[4];
    #pragma unroll
    for (int mi = 0; mi < 4; ++mi)
      af[mi] = *(const i32x4*)(As[cur] + (wm + mi * 16 + lr) * BKK + kg);
    #pragma unroll
    for (int ni = 0; ni < 4; ++ni)
      bf[ni] = *(const i32x4*)(Bs[cur] + (wn + ni * 16 + lr) * BKK + kg);
    #pragma unroll
    for (int mi = 0; mi < 4; ++mi)
      #pragma unroll
      for (int ni = 0; ni < 4; ++ni)
        asm("v_mfma_f32_16x16x32_bf16 %0, %1, %2, %0"
            : "+v"(acc[mi][ni]) : "v"(bf[ni]), "v"(af[mi]));  // SWAPPED
    __syncthreads();                    // drains vmcnt(0): next buf ready
    cur ^= 1;
  }

  // Swapped-operand fragment: lane holds row = ..+ (lane&15),
  // cols = ..+ (lane>>4)*4 + r  (4 consecutive).
  int cm = lane & 15;
  int cg = (lane >> 4) << 2;
  #pragma unroll
  for (int mi = 0; mi < 4; ++mi) {
    long row = m0 + wm + mi * 16 + cm;
    #pragma unroll
    for (int ni = 0; ni < 4; ++ni) {
      int col = n0 + wn + ni * 16 + cg;
      f32x4 v = acc[mi][ni];
      if (MODE == 2) {                       // N multiple of 128, no tail
        #pragma unroll
        for (int r = 0; r < 4; ++r) v[r] *= alpha;
        *(f32x4*)((float*)Cv + coff + row * (long)ldc + col) = v;
      } else if (MODE == 0 || MODE == 1) {   // N multiple of 128, no tail
        f32x4 bv = *(const f32x4*)(bias + col);
        u16x4 o;
        #pragma unroll
        for (int r = 0; r < 4; ++r) {
          float t = v[r] + bv[r];
          if (MODE == 1) t = fmaxf(t, 0.f);
          o[r] = f2bf(t);
        }
        *(u16x4*)((unsigned short*)Cv + coff + row * (long)ldc + col) = o;
      } else {                               // MODE 3 / 4, may have N tail
        float* cp = (float*)Cv + coff + row * (long)ldc + col;
        if (col + 4 <= N) {
          f32x4 bv = bias ? *(const f32x4*)(bias + col)
                          : f32x4{0.f, 0.f, 0.f, 0.f};
          if (MODE == 3) {
            f32x4 old = *(f32x4*)cp;
            #pragma unroll
            for (int r = 0; r < 4; ++r) old[r] += v[r] + bv[r];
            *(f32x4*)cp = old;
          } else {
            f32x4 o;
            #pragma unroll
            for (int r = 0; r < 4; ++r) o[r] = v[r] + bv[r];
            *(f32x4*)cp = o;
          }
        } else {
          #pragma unroll
          for (int r = 0; r < 4; ++r) {
            if (col + r < N) {
              float bvr = bias ? bias[col + r] : 0.f;
              if (MODE == 3) cp[r] += v[r] + bvr;
              else           cp[r] = v[r] + bvr;
            }
          }
        }
      }
    }
  }
}

extern "C" void kernel_launch(void* const* d_in, const int* in_sizes, int n_in,
                              void* d_out, int out_size, void* d_ws, size_t ws_size,
                              hipStream_t stream) {
  const int*   x       = (const int*)  d_in[0];
  const float* tok_emb = (const float*)d_in[1];
  const float* pos_emb = (const float*)d_in[2];
  const float* ln1_s   = (const float*)d_in[3];
  const float* ln1_b   = (const float*)d_in[4];
  const float* qkv_w   = (const float*)d_in[5];
  const float* qkv_b   = (const float*)d_in[6];
  const float* ln2_s   = (const float*)d_in[7];
  const float* ln2_b   = (const float*)d_in[8];
  const float* fc_w    = (const float*)d_in[9];
  const float* fc_b    = (const float*)d_in[10];
  const float* proj_w  = (const float*)d_in[11];
  const float* proj_b  = (const float*)d_in[12];
  const float* lnf_s   = (const float*)d_in[13];
  const float* lnf_b   = (const float*)d_in[14];
  const float* head_w  = (const float*)d_in[15];
  const float* head_b  = (const float*)d_in[16];

  char* ws = (char*)d_ws;
  size_t off = 0;
  auto alloc = [&](size_t bytes) {
    char* p = ws + off;
    off += (bytes + 255) & ~(size_t)255;
    return p;
  };
  float*          h   = (float*)         alloc((size_t)NTOK * D_MODEL * 4);
  unsigned short* lnb = (unsigned short*)alloc((size_t)NTOK * D_MODEL * 2);
  unsigned short* qkv = (unsigned short*)alloc((size_t)NTOK * 2304 * 2);
  unsigned short* vt  = (unsigned short*)alloc((size_t)16 * DHEAD * SEQ * 2);
  unsigned short* mid = (unsigned short*)alloc((size_t)NTOK * 3072 * 2);
  float*          S   = (float*)         alloc((size_t)16 * SEQ * SEQ * 4);
  unsigned short* P   = (unsigned short*)alloc((size_t)16 * SEQ * SEQ * 2);
  unsigned short* wtq = (unsigned short*)alloc((size_t)2304 * 768 * 2);
  unsigned short* wtf = (unsigned short*)alloc((size_t)3072 * 768 * 2);
  unsigned short* wtp = (unsigned short*)alloc((size_t)768 * 3072 * 2);
  unsigned short* wth = (unsigned short*)alloc((size_t)50304 * 768 * 2);

  embed_kernel<<<NTOK, 256, 0, stream>>>(x, tok_emb, pos_emb, h);

  const float rscale = 0.07216878364870323f;  // 1/sqrt(192)

  for (int l = 0; l < NLAYER; ++l) {
    // ---- all three weight transposes in one launch ----
    wtrans3_kernel<<<6336, 256, 0, stream>>>(
        qkv_w + (long)l * 768 * 2304, fc_w + (long)l * 768 * 3072,
        proj_w + (long)l * 3072 * 768, wtq, wtf, wtp);
    // ---- attention ----
    ln_kernel<<<NTOK, 256, 0, stream>>>(h, ln1_s + l * 768, ln1_b + l * 768, lnb);
    gemm_kernel<0><<<dim3(18, 32, 1), 256, 0, stream>>>(
        lnb, 768, wtq, 768, qkv_b + l * 2304, qkv, 2304,
        4096, 2304, 768, 1, 0, 0, 0, 0, 0, 0, 1.0f, 0, 0);
    vt_kernel<<<dim3(32, 6, 16), dim3(32, 8), 0, stream>>>(qkv, vt);
    // S = scale * Q K^T   (batched over 16 (b,h); skip upper-tri blocks)
    gemm_kernel<2><<<dim3(8, 8, 16), 256, 0, stream>>>(
        qkv, 2304, qkv + 768, 2304, nullptr, S, 1024,
        1024, 1024, 192, 4,
        (long)1024 * 2304, 192, (long)1024 * 2304, 192,
        (long)4 * 1024 * 1024, (long)1024 * 1024, rscale, 1, 0);
    softmax_kernel<<<16384, 256, 0, stream>>>(S, P);
    // h += P V   (k-limited by causality)
    gemm_kernel<3><<<dim3(2, 8, 16), 256, 0, stream>>>(
        P, 1024, vt, 1024, nullptr, h, 768,
        1024, 192, 1024, 4,
        (long)4 * 1024 * 1024, (long)1024 * 1024,
        (long)4 * 192 * 1024, (long)192 * 1024,
        (long)1024 * 768, 192, 1.0f, 2, 0);
    // ---- MLP ----
    ln_kernel<<<NTOK, 256, 0, stream>>>(h, ln2_s + l * 768, ln2_b + l * 768, lnb);
    gemm_kernel<1><<<dim3(24, 32, 1), 256, 0, stream>>>(
        lnb, 768, wtf, 768, fc_b + l * 3072, mid, 3072,
        4096, 3072, 768, 1, 0, 0, 0, 0, 0, 0, 1.0f, 0, 0);
    gemm_kernel<3><<<dim3(6, 32, 1), 256, 0, stream>>>(
        mid, 3072, wtp, 3072, proj_b + l * 768, h, 768,
        4096, 768, 3072, 1, 0, 0, 0, 0, 0, 0, 1.0f, 0, 0);
  }

  // ---- final LN + head ----
  wtrans_kernel<<<dim3(1571, 24), dim3(32, 8), 0, stream>>>(head_w, wth, 768, 50257);
  ln_kernel<<<NTOK, 256, 0, stream>>>(h, lnf_s, lnf_b, lnb);
  // m-chunk-per-XCD swizzle: 4 M-blocks per XCD, N fastest -> A-panel L2-
  // resident, head weight streamed once per XCD (L3-shared across XCDs).
  gemm_kernel<4><<<dim3(32 * 393, 1, 1), 256, 0, stream>>>(
      lnb, 768, wth, 768, head_b, (float*)d_out, 50257,
      4096, 50257, 768, 1, 0, 0, 0, 0, 0, 0, 1.0f, 0, 32);
}

// Round 6
// 3212.885 us; speedup vs baseline: 1.4034x; 1.0187x over previous
//
#include <hip/hip_runtime.h>
#include <stdint.h>

#define D_MODEL 768
#define NHEAD 4
#define DHEAD 192
#define SEQ 1024
#define NLAYER 12
#define NTOK 4096
#define NVOCAB 50257

typedef __attribute__((ext_vector_type(4))) float f32x4;
typedef __attribute__((ext_vector_type(4))) int i32x4;
typedef __attribute__((ext_vector_type(4))) unsigned short u16x4;

__device__ __forceinline__ unsigned short f2bf(float f) {
  unsigned u = __builtin_bit_cast(unsigned, f);
  u += 0x7FFFu + ((u >> 16) & 1u);
  return (unsigned short)(u >> 16);
}

// async global->LDS, 16B per lane; lds base must be wave-uniform
#define GLDS(src, dst)                                                   \
  __builtin_amdgcn_global_load_lds(                                      \
      (const __attribute__((address_space(1))) void*)(src),              \
      (__attribute__((address_space(3))) void*)(dst), 16, 0, 0)

#define FENCE asm volatile("" ::: "memory")
#define BAR()                         \
  do {                                \
    FENCE;                            \
    __builtin_amdgcn_s_barrier();     \
    FENCE;                            \
  } while (0)

// ---------------- embedding ----------------
__global__ __launch_bounds__(256) void embed_kernel(
    const int* __restrict__ x, const float* __restrict__ tok,
    const float* __restrict__ pos, float* __restrict__ h) {
  int row = blockIdx.x;
  int t = row & (SEQ - 1);
  int id = x[row];
  const float* tp = tok + (long)id * D_MODEL;
  const float* pp = pos + (long)t * D_MODEL;
  float* hp = h + (long)row * D_MODEL;
  for (int j = threadIdx.x; j < D_MODEL; j += 256)
    hp[j] = tp[j] + pp[j];
}

// ---------------- layernorm (f32 in) -> bf16 out ----------------
__global__ __launch_bounds__(256) void ln_kernel(
    const float* __restrict__ h, const float* __restrict__ sc,
    const float* __restrict__ sh, unsigned short* __restrict__ out) {
  __shared__ float red[4];
  int row = blockIdx.x;
  const float* x = h + (long)row * D_MODEL;
  int tid = threadIdx.x;
  float v0 = x[tid], v1 = x[tid + 256], v2 = x[tid + 512];
  float s = v0 + v1 + v2;
  for (int o = 32; o > 0; o >>= 1) s += __shfl_xor(s, o);
  if ((tid & 63) == 0) red[tid >> 6] = s;
  __syncthreads();
  float mean = (red[0] + red[1] + red[2] + red[3]) * (1.0f / D_MODEL);
  __syncthreads();
  float d0 = v0 - mean, d1 = v1 - mean, d2 = v2 - mean;
  float q = d0 * d0 + d1 * d1 + d2 * d2;
  for (int o = 32; o > 0; o >>= 1) q += __shfl_xor(q, o);
  if ((tid & 63) == 0) red[tid >> 6] = q;
  __syncthreads();
  float var = (red[0] + red[1] + red[2] + red[3]) * (1.0f / D_MODEL);
  float r = rsqrtf(var + 1e-5f);
  unsigned short* op = out + (long)row * D_MODEL;
  op[tid]       = f2bf(d0 * r * sc[tid]       + sh[tid]);
  op[tid + 256] = f2bf(d1 * r * sc[tid + 256] + sh[tid + 256]);
  op[tid + 512] = f2bf(d2 * r * sc[tid + 512] + sh[tid + 512]);
}

// ------- fused per-layer weight transpose -------
__global__ __launch_bounds__(256) void wtrans3_kernel(
    const float* __restrict__ qw, const float* __restrict__ fw,
    const float* __restrict__ pw, unsigned short* __restrict__ tq,
    unsigned short* __restrict__ tf, unsigned short* __restrict__ tp) {
  __shared__ unsigned short tile[32][33];
  int bid = blockIdx.x;
  const float* src; unsigned short* dst; int K, N, nb;
  if (bid < 1728)               { src = qw; dst = tq; K = 768;  N = 2304; nb = 72; }
  else if ((bid -= 1728) < 2304){ src = fw; dst = tf; K = 768;  N = 3072; nb = 96; }
  else { bid -= 2304;             src = pw; dst = tp; K = 3072; N = 768;  nb = 24; }
  int n0 = (bid % nb) * 32, k0 = (bid / nb) * 32;
  int tx = threadIdx.x & 31, ty = threadIdx.x >> 5;
  #pragma unroll
  for (int i = 0; i < 4; ++i) {
    int k = k0 + ty + i * 8;
    tile[ty + i * 8][tx] = f2bf(src[(long)k * N + n0 + tx]);
  }
  __syncthreads();
  #pragma unroll
  for (int i = 0; i < 4; ++i) {
    int nn = n0 + ty + i * 8;
    dst[(long)nn * K + k0 + tx] = tile[tx][ty + i * 8];
  }
}

// ---------------- head weight transpose (N tail) ----------------
__global__ __launch_bounds__(256) void wtrans_kernel(
    const float* __restrict__ w, unsigned short* __restrict__ wt, int K, int N) {
  __shared__ unsigned short tile[32][33];
  int n0 = blockIdx.x * 32, k0 = blockIdx.y * 32;
  int tx = threadIdx.x, ty = threadIdx.y;
  int n = n0 + tx; if (n >= N) n = N - 1;
  #pragma unroll
  for (int i = 0; i < 4; ++i) {
    int k = k0 + ty + i * 8;
    tile[ty + i * 8][tx] = f2bf(w[(long)k * N + n]);
  }
  __syncthreads();
  #pragma unroll
  for (int i = 0; i < 4; ++i) {
    int nn = n0 + ty + i * 8;
    if (nn < N) wt[(long)nn * K + k0 + tx] = tile[tx][ty + i * 8];
  }
}

// ---------------- V transpose ----------------
__global__ __launch_bounds__(256) void vt_kernel(
    const unsigned short* __restrict__ qkv, unsigned short* __restrict__ vt) {
  __shared__ unsigned short tile[32][33];
  int bh = blockIdx.z, b = bh >> 2, hh = bh & 3;
  int t0 = blockIdx.x * 32, f0 = blockIdx.y * 32;
  int tx = threadIdx.x, ty = threadIdx.y;
  const unsigned short* src = qkv + (long)b * SEQ * 2304 + 2 * D_MODEL + hh * DHEAD;
  #pragma unroll
  for (int i = 0; i < 4; ++i) {
    int t = t0 + ty + i * 8;
    tile[ty + i * 8][tx] = src[(long)t * 2304 + f0 + tx];
  }
  __syncthreads();
  unsigned short* dst = vt + (long)bh * DHEAD * SEQ;
  #pragma unroll
  for (int i = 0; i < 4; ++i) {
    int f = f0 + ty + i * 8;
    dst[(long)f * SEQ + t0 + tx] = tile[tx][ty + i * 8];
  }
}

// ------- causal row softmax -------
__global__ __launch_bounds__(256) void softmax_kernel(
    const float* __restrict__ S, unsigned short* __restrict__ P) {
  __shared__ float red[4];
  long rid = blockIdx.x;
  int q = (int)(rid & (SEQ - 1));
  int tid = threadIdx.x;
  int i0 = tid * 4;
  f32x4 v;
  if (i0 <= q) {
    v = *(const f32x4*)(S + rid * SEQ + i0);
  } else {
    v = f32x4{-3.0e38f, -3.0e38f, -3.0e38f, -3.0e38f};
  }
  float m = -3.0e38f;
  #pragma unroll
  for (int j = 0; j < 4; ++j) {
    if (i0 + j > q) v[j] = -3.0e38f;
    m = fmaxf(m, v[j]);
  }
  for (int o = 32; o > 0; o >>= 1) m = fmaxf(m, __shfl_xor(m, o));
  if ((tid & 63) == 0) red[tid >> 6] = m;
  __syncthreads();
  m = fmaxf(fmaxf(red[0], red[1]), fmaxf(red[2], red[3]));
  __syncthreads();
  float e[4];
  float sum = 0.f;
  #pragma unroll
  for (int j = 0; j < 4; ++j) {
    e[j] = (i0 + j > q) ? 0.f : __expf(v[j] - m);
    sum += e[j];
  }
  for (int o = 32; o > 0; o >>= 1) sum += __shfl_xor(sum, o);
  if ((tid & 63) == 0) red[tid >> 6] = sum;
  __syncthreads();
  float inv = 1.0f / (red[0] + red[1] + red[2] + red[3]);
  if ((i0 >> 7) <= (q >> 7)) {
    u16x4 out;
    #pragma unroll
    for (int j = 0; j < 4; ++j) out[j] = f2bf(e[j] * inv);
    *(u16x4*)(P + rid * SEQ + i0) = out;
  }
}

// ======================= 256x256 8-phase GEMM =======================
// C = A[M][K](bf16) x B[N][K](bf16)^T.  8 waves (2M x 4N), BK=64,
// double-buffered 128KB LDS, half-tile staging (one 128x64 half per phase),
// counted vmcnt(6) once per K-tile, setprio around MFMA clusters,
// XOR-swizzled LDS (linear gload_lds dest + inverse-swizzled global src).
// Wave layout: wave wm covers C-rows {wm*64..+63} u {128+wm*64..+63};
// wave wn covers C-cols {wn*32..+31} u {128+wn*32..+31}.  So A-half0 holds
// m-frags 0-3, A-half1 frags 4-7; B-half0 n-frags 0-1, B-half1 frags 2-3.
// Phase quadrants: P1 (f0-3,g0-1)  P2 (f0-3,g2-3)  P3 (f4-7,g2-3)
//                  P4 (f4-7,g0-1)  -- b01 stays live P1->P4 (no re-read).
// Stage schedule (issue): P1: (t+1).A1   P2: (t+2).A0   P3: (t+2).B0
//                         P4: (t+2).B1 + vmcnt(6)
// vmcnt(6) leaves the 3 newest halves (all t+2) outstanding => all of t+1
// landed before its first read.  Every stage targets a region whose last
// reader finished >= one closing barrier earlier (safe, see derivation).
// MODE 0: bf16 = acc+bias (QKV)  MODE 1: bf16 = relu(acc+bias) (FC)
// MODE 4: f32 = acc+bias (head, N-tail masked)

template<int MODE>
__global__ __launch_bounds__(512, 2) void gemm256_kernel(
    const unsigned short* __restrict__ A,   // [M][K]
    const unsigned short* __restrict__ B,   // [N][K]
    const float* __restrict__ bias,
    void* __restrict__ Cv, int ldc,
    int M, int N, int K, int mb) {
  // [buf][mat 0=A 1=B][half][128*64]
  __shared__ __align__(16) unsigned short lds[2][2][2][128 * 64];

  int tid = threadIdx.x;
  int lane = tid & 63;
  int wid = tid >> 6;
  int wm = wid >> 2;          // 0..1
  int wn = wid & 3;           // 0..3

  // m-chunk-per-XCD swizzle (grid = mb*nb, mb % 8 == 0 via mb=16)
  int bid = blockIdx.x;
  int mpx = mb >> 3;
  int xcd = bid & 7;
  int c = bid >> 3;
  int m0 = (xcd * mpx + (c & (mpx - 1))) * 256;
  int n0 = (c / mpx) * 256;

  // ---- staging: one 128x64 half-tile, 2 gload_lds per thread ----
  // linear LDS dest, inverse-swizzled global source column:
  // slot(row r, colbyte cb) holds element(r, cb ^ ((r&7)<<4))
  auto stageA = [&](int buf, int half, int kt) {
    const unsigned short* src = A + (long)(m0 + half * 128) * K + kt * 64;
    #pragma unroll
    for (int i = 0; i < 2; ++i) {
      int chunk = i * 8 + wid;
      int r = chunk * 8 + (lane >> 3);
      int cc = ((lane & 7) ^ (lane >> 3)) << 3;
      GLDS(src + (long)r * K + cc, &lds[buf][0][half][chunk * 512]);
    }
  };
  auto stageB = [&](int buf, int half, int kt) {
    #pragma unroll
    for (int i = 0; i < 2; ++i) {
      int chunk = i * 8 + wid;
      int r = chunk * 8 + (lane >> 3);
      int cc = ((lane & 7) ^ (lane >> 3)) << 3;
      int rg = n0 + half * 128 + r;
      if (rg >= N) rg = N - 1;                 // head tail clamp
      GLDS(B + (long)rg * K + kt * 64 + cc, &lds[buf][1][half][chunk * 512]);
    }
  };

  // ---- swizzled fragment reads ----
  auto lda_frag = [&](int buf, int f, int s) -> i32x4 {
    int r = wm * 64 + (f & 3) * 16 + (lane & 15);
    int kb = s * 64 + ((lane >> 4) << 4);
    int off = r * 128 + (kb ^ ((r & 7) << 4));
    return *(const i32x4*)((const char*)&lds[buf][0][f >> 2][0] + off);
  };
  auto ldb_frag = [&](int buf, int g, int s) -> i32x4 {
    int r = wn * 32 + (g & 1) * 16 + (lane & 15);
    int kb = s * 64 + ((lane >> 4) << 4);
    int off = r * 128 + (kb ^ ((r & 7) << 4));
    return *(const i32x4*)((const char*)&lds[buf][1][g >> 1][0] + off);
  };

  f32x4 acc[8][4] = {};
  i32x4 a[4][2], b[4][2];

  int nt = K / 64;            // >= 2, even for all our shapes

  // prologue: tile0 fully, tile1 A0,B0,B1
  stageA(0, 0, 0); stageB(0, 0, 0); stageB(0, 1, 0); stageA(0, 1, 0);
  stageA(1, 0, 1); stageB(1, 0, 1); stageB(1, 1, 1);
  asm volatile("s_waitcnt vmcnt(6)" ::: "memory");
  BAR();

  for (int t = 0; t < nt; ++t) {
    int buf = t & 1, nbuf = buf ^ 1;
    // ---- P1: read a[f0-3], b[g0-1]; stage (t+1).A1 ----
    #pragma unroll
    for (int fi = 0; fi < 4; ++fi) {
      a[fi][0] = lda_frag(buf, fi, 0);
      a[fi][1] = lda_frag(buf, fi, 1);
    }
    #pragma unroll
    for (int gi = 0; gi < 2; ++gi) {
      b[gi][0] = ldb_frag(buf, gi, 0);
      b[gi][1] = ldb_frag(buf, gi, 1);
    }
    if (t + 1 < nt) stageA(nbuf, 1, t + 1);
    BAR();
    __builtin_amdgcn_s_setprio(1);
    #pragma unroll
    for (int s = 0; s < 2; ++s)
      #pragma unroll
      for (int fi = 0; fi < 4; ++fi)
        #pragma unroll
        for (int gi = 0; gi < 2; ++gi)
          asm("v_mfma_f32_16x16x32_bf16 %0, %1, %2, %0"
              : "+v"(acc[fi][gi]) : "v"(b[gi][s]), "v"(a[fi][s]));
    __builtin_amdgcn_s_setprio(0);
    BAR();
    // ---- P2: read b[g2-3]; stage (t+2).A0 ----
    #pragma unroll
    for (int gi = 2; gi < 4; ++gi) {
      b[gi][0] = ldb_frag(buf, gi, 0);
      b[gi][1] = ldb_frag(buf, gi, 1);
    }
    if (t + 2 < nt) stageA(buf, 0, t + 2);
    BAR();
    __builtin_amdgcn_s_setprio(1);
    #pragma unroll
    for (int s = 0; s < 2; ++s)
      #pragma unroll
      for (int fi = 0; fi < 4; ++fi)
        #pragma unroll
        for (int gi = 2; gi < 4; ++gi)
          asm("v_mfma_f32_16x16x32_bf16 %0, %1, %2, %0"
              : "+v"(acc[fi][gi]) : "v"(b[gi][s]), "v"(a[fi][s]));
    __builtin_amdgcn_s_setprio(0);
    BAR();
    // ---- P3: read a[f4-7]; stage (t+2).B0 ----
    #pragma unroll
    for (int fi = 0; fi < 4; ++fi) {
      a[fi][0] = lda_frag(buf, 4 + fi, 0);
      a[fi][1] = lda_frag(buf, 4 + fi, 1);
    }
    if (t + 2 < nt) stageB(buf, 0, t + 2);
    BAR();
    __builtin_amdgcn_s_setprio(1);
    #pragma unroll
    for (int s = 0; s < 2; ++s)
      #pragma unroll
      for (int fi = 0; fi < 4; ++fi)
        #pragma unroll
        for (int gi = 2; gi < 4; ++gi)
          asm("v_mfma_f32_16x16x32_bf16 %0, %1, %2, %0"
              : "+v"(acc[4 + fi][gi]) : "v"(b[gi][s]), "v"(a[fi][s]));
    __builtin_amdgcn_s_setprio(0);
    BAR();
    // ---- P4: stage (t+2).B1; counted vmcnt ----
    if (t + 2 < nt) {
      stageB(buf, 1, t + 2);
      asm volatile("s_waitcnt vmcnt(6)" ::: "memory");
    } else if (t + 1 < nt) {
      asm volatile("s_waitcnt vmcnt(0)" ::: "memory");
    }
    BAR();
    __builtin_amdgcn_s_setprio(1);
    #pragma unroll
    for (int s = 0; s < 2; ++s)
      #pragma unroll
      for (int fi = 0; fi < 4; ++fi)
        #pragma unroll
        for (int gi = 0; gi < 2; ++gi)
          asm("v_mfma_f32_16x16x32_bf16 %0, %1, %2, %0"
              : "+v"(acc[4 + fi][gi]) : "v"(b[gi][s]), "v"(a[fi][s]));
    __builtin_amdgcn_s_setprio(0);
    BAR();
  }

  // ---- epilogue: lane holds row = base+(lane&15), 4 consecutive cols ----
  int cr = lane & 15;
  int cg = (lane >> 4) << 2;
  #pragma unroll
  for (int f = 0; f < 8; ++f) {
    long row = m0 + wm * 64 + (f & 3) * 16 + (f >> 2) * 128 + cr;
    #pragma unroll
    for (int g = 0; g < 4; ++g) {
      int col = n0 + wn * 32 + (g & 1) * 16 + (g >> 1) * 128 + cg;
      f32x4 v = acc[f][g];
      if (MODE == 0 || MODE == 1) {          // N multiple of 256, no tail
        f32x4 bv = *(const f32x4*)(bias + col);
        u16x4 o;
        #pragma unroll
        for (int r = 0; r < 4; ++r) {
          float tt = v[r] + bv[r];
          if (MODE == 1) tt = fmaxf(tt, 0.f);
          o[r] = f2bf(tt);
        }
        *(u16x4*)((unsigned short*)Cv + row * (long)ldc + col) = o;
      } else {                               // MODE 4, masked tail
        float* cp = (float*)Cv + row * (long)ldc + col;
        if (col + 4 <= N) {
          f32x4 bv = *(const f32x4*)(bias + col);
          f32x4 o;
          #pragma unroll
          for (int r = 0; r < 4; ++r) o[r] = v[r] + bv[r];
          *(f32x4*)cp = o;
        } else {
          #pragma unroll
          for (int r = 0; r < 4; ++r)
            if (col + r < N) cp[r] = v[r] + bias[col + r];
        }
      }
    }
  }
}

// ---------------- 128x128 GEMM (kept for S / PV / PROJ) ----------------
#define BM 128
#define BN 128
#define BKK 32

template<int MODE>
__global__ __launch_bounds__(256) void gemm_kernel(
    const unsigned short* __restrict__ A, int lda,
    const unsigned short* __restrict__ B, int ldb,
    const float* __restrict__ bias,
    void* __restrict__ Cv, int ldc,
    int M, int N, int K,
    int NI, long sAo, long sAi, long sBo, long sBi,
    long sCo, long sCi, float alpha, int causal, int mblocks) {
  __shared__ __align__(16) unsigned short As[2][BM * BKK];
  __shared__ __align__(16) unsigned short Bs[2][BN * BKK];
  int z = blockIdx.z;
  int zo = z / NI, zi = z - zo * NI;
  A += zo * sAo + zi * sAi;
  B += zo * sBo + zi * sBi;
  long coff = zo * sCo + zi * sCi;

  int m0, n0;
  if (mblocks > 0) {
    int bid = blockIdx.x;
    int mpx = mblocks >> 3;
    int xcd = bid & 7;
    int c = bid >> 3;
    m0 = (xcd * mpx + (c & (mpx - 1))) * BM;
    n0 = (c / mpx) * BN;
  } else {
    m0 = blockIdx.y * BM;
    n0 = blockIdx.x * BN;
  }
  if (causal == 1 && n0 > m0 + BM - 1) return;
  int kmax = (causal == 2) ? min(K, m0 + BM) : K;

  int tid = threadIdx.x;
  int lane = tid & 63;
  int wave = tid >> 6;
  int wm = (wave >> 1) * 64;
  int wn = (wave & 1) * 64;

  auto stage = [&](int buf, int k0) {
    #pragma unroll
    for (int i = 0; i < 2; ++i) {
      int c0 = i * 256 + wave * 64;
      int cc = c0 + lane;
      int row = cc >> 2;
      int ko = (cc & 3) << 3;
      GLDS(A + (long)(m0 + row) * lda + k0 + ko, As[buf] + c0 * 8);
      int rg = n0 + row; if (rg >= N) rg = N - 1;
      GLDS(B + (long)rg * ldb + k0 + ko, Bs[buf] + c0 * 8);
    }
  };

  f32x4 acc[4][4] = {};
  int nt = kmax / BKK;
  stage(0, 0);
  __syncthreads();
  int cur = 0;
  for (int t = 0; t < nt; ++t) {
    if (t + 1 < nt) stage(cur ^ 1, (t + 1) * BKK);
    int lr = lane & 15;
    int kg = (lane >> 4) << 3;
    i32x4 af[4], bf[4];
    #pragma unroll
    for (int mi = 0; mi < 4; ++mi)
      af[mi] = *(const i32x4*)(As[cur] + (wm + mi * 16 + lr) * BKK + kg);
    #pragma unroll
    for (int ni = 0; ni < 4; ++ni)
      bf[ni] = *(const i32x4*)(Bs[cur] + (wn + ni * 16 + lr) * BKK + kg);
    #pragma unroll
    for (int mi = 0; mi < 4; ++mi)
      #pragma unroll
      for (int ni = 0; ni < 4; ++ni)
        asm("v_mfma_f32_16x16x32_bf16 %0, %1, %2, %0"
            : "+v"(acc[mi][ni]) : "v"(bf[ni]), "v"(af[mi]));
    __syncthreads();
    cur ^= 1;
  }

  int cm = lane & 15;
  int cg = (lane >> 4) << 2;
  #pragma unroll
  for (int mi = 0; mi < 4; ++mi) {
    long row = m0 + wm + mi * 16 + cm;
    #pragma unroll
    for (int ni = 0; ni < 4; ++ni) {
      int col = n0 + wn + ni * 16 + cg;
      f32x4 v = acc[mi][ni];
      if (MODE == 2) {
        #pragma unroll
        for (int r = 0; r < 4; ++r) v[r] *= alpha;
        *(f32x4*)((float*)Cv + coff + row * (long)ldc + col) = v;
      } else if (MODE == 0 || MODE == 1) {
        f32x4 bv = *(const f32x4*)(bias + col);
        u16x4 o;
        #pragma unroll
        for (int r = 0; r < 4; ++r) {
          float t = v[r] + bv[r];
          if (MODE == 1) t = fmaxf(t, 0.f);
          o[r] = f2bf(t);
        }
        *(u16x4*)((unsigned short*)Cv + coff + row * (long)ldc + col) = o;
      } else {
        float* cp = (float*)Cv + coff + row * (long)ldc + col;
        if (col + 4 <= N) {
          f32x4 bv = bias ? *(const f32x4*)(bias + col)
                          : f32x4{0.f, 0.f, 0.f, 0.f};
          if (MODE == 3) {
            f32x4 old = *(f32x4*)cp;
            #pragma unroll
            for (int r = 0; r < 4; ++r) old[r] += v[r] + bv[r];
            *(f32x4*)cp = old;
          } else {
            f32x4 o;
            #pragma unroll
            for (int r = 0; r < 4; ++r) o[r] = v[r] + bv[r];
            *(f32x4*)cp = o;
          }
        } else {
          #pragma unroll
          for (int r = 0; r < 4; ++r) {
            if (col + r < N) {
              float bvr = bias ? bias[col + r] : 0.f;
              if (MODE == 3) cp[r] += v[r] + bvr;
              else           cp[r] = v[r] + bvr;
            }
          }
        }
      }
    }
  }
}

extern "C" void kernel_launch(void* const* d_in, const int* in_sizes, int n_in,
                              void* d_out, int out_size, void* d_ws, size_t ws_size,
                              hipStream_t stream) {
  const int*   x       = (const int*)  d_in[0];
  const float* tok_emb = (const float*)d_in[1];
  const float* pos_emb = (const float*)d_in[2];
  const float* ln1_s   = (const float*)d_in[3];
  const float* ln1_b   = (const float*)d_in[4];
  const float* qkv_w   = (const float*)d_in[5];
  const float* qkv_b   = (const float*)d_in[6];
  const float* ln2_s   = (const float*)d_in[7];
  const float* ln2_b   = (const float*)d_in[8];
  const float* fc_w    = (const float*)d_in[9];
  const float* fc_b    = (const float*)d_in[10];
  const float* proj_w  = (const float*)d_in[11];
  const float* proj_b  = (const float*)d_in[12];
  const float* lnf_s   = (const float*)d_in[13];
  const float* lnf_b   = (const float*)d_in[14];
  const float* head_w  = (const float*)d_in[15];
  const float* head_b  = (const float*)d_in[16];

  char* ws = (char*)d_ws;
  size_t off = 0;
  auto alloc = [&](size_t bytes) {
    char* p = ws + off;
    off += (bytes + 255) & ~(size_t)255;
    return p;
  };
  float*          h   = (float*)         alloc((size_t)NTOK * D_MODEL * 4);
  unsigned short* lnb = (unsigned short*)alloc((size_t)NTOK * D_MODEL * 2);
  unsigned short* qkv = (unsigned short*)alloc((size_t)NTOK * 2304 * 2);
  unsigned short* vt  = (unsigned short*)alloc((size_t)16 * DHEAD * SEQ * 2);
  unsigned short* mid = (unsigned short*)alloc((size_t)NTOK * 3072 * 2);
  float*          S   = (float*)         alloc((size_t)16 * SEQ * SEQ * 4);
  unsigned short* P   = (unsigned short*)alloc((size_t)16 * SEQ * SEQ * 2);
  unsigned short* wtq = (unsigned short*)alloc((size_t)2304 * 768 * 2);
  unsigned short* wtf = (unsigned short*)alloc((size_t)3072 * 768 * 2);
  unsigned short* wtp = (unsigned short*)alloc((size_t)768 * 3072 * 2);
  unsigned short* wth = (unsigned short*)alloc((size_t)50304 * 768 * 2);

  embed_kernel<<<NTOK, 256, 0, stream>>>(x, tok_emb, pos_emb, h);

  const float rscale = 0.07216878364870323f;  // 1/sqrt(192)

  for (int l = 0; l < NLAYER; ++l) {
    wtrans3_kernel<<<6336, 256, 0, stream>>>(
        qkv_w + (long)l * 768 * 2304, fc_w + (long)l * 768 * 3072,
        proj_w + (long)l * 3072 * 768, wtq, wtf, wtp);
    // ---- attention ----
    ln_kernel<<<NTOK, 256, 0, stream>>>(h, ln1_s + l * 768, ln1_b + l * 768, lnb);
    gemm256_kernel<0><<<16 * 9, 512, 0, stream>>>(
        lnb, wtq, qkv_b + l * 2304, qkv, 2304, 4096, 2304, 768, 16);
    vt_kernel<<<dim3(32, 6, 16), dim3(32, 8), 0, stream>>>(qkv, vt);
    gemm_kernel<2><<<dim3(8, 8, 16), 256, 0, stream>>>(
        qkv, 2304, qkv + 768, 2304, nullptr, S, 1024,
        1024, 1024, 192, 4,
        (long)1024 * 2304, 192, (long)1024 * 2304, 192,
        (long)4 * 1024 * 1024, (long)1024 * 1024, rscale, 1, 0);
    softmax_kernel<<<16384, 256, 0, stream>>>(S, P);
    gemm_kernel<3><<<dim3(2, 8, 16), 256, 0, stream>>>(
        P, 1024, vt, 1024, nullptr, h, 768,
        1024, 192, 1024, 4,
        (long)4 * 1024 * 1024, (long)1024 * 1024,
        (long)4 * 192 * 1024, (long)192 * 1024,
        (long)1024 * 768, 192, 1.0f, 2, 0);
    // ---- MLP ----
    ln_kernel<<<NTOK, 256, 0, stream>>>(h, ln2_s + l * 768, ln2_b + l * 768, lnb);
    gemm256_kernel<1><<<16 * 12, 512, 0, stream>>>(
        lnb, wtf, fc_b + l * 3072, mid, 3072, 4096, 3072, 768, 16);
    gemm_kernel<3><<<dim3(6, 32, 1), 256, 0, stream>>>(
        mid, 3072, wtp, 3072, proj_b + l * 768, h, 768,
        4096, 768, 3072, 1, 0, 0, 0, 0, 0, 0, 1.0f, 0, 0);
  }

  // ---- final LN + head ----
  wtrans_kernel<<<dim3(1571, 24), dim3(32, 8), 0, stream>>>(head_w, wth, 768, 50257);
  ln_kernel<<<NTOK, 256, 0, stream>>>(h, lnf_s, lnf_b, lnb);
  gemm256_kernel<4><<<16 * 197, 512, 0, stream>>>(
      lnb, wth, head_b, (float*)d_out, 50257, 4096, 50257, 768, 16);
}

// Round 10
// 3181.108 us; speedup vs baseline: 1.4174x; 1.0100x over previous
//
#include <hip/hip_runtime.h>
#include <stdint.h>

#define D_MODEL 768
#define NHEAD 4
#define DHEAD 192
#define SEQ 1024
#define NLAYER 12
#define NTOK 4096
#define NVOCAB 50257

typedef __attribute__((ext_vector_type(4))) float f32x4;
typedef __attribute__((ext_vector_type(4))) int i32x4;
typedef __attribute__((ext_vector_type(4))) unsigned short u16x4;

__device__ __forceinline__ unsigned short f2bf(float f) {
  unsigned u = __builtin_bit_cast(unsigned, f);
  u += 0x7FFFu + ((u >> 16) & 1u);
  return (unsigned short)(u >> 16);
}

// async global->LDS, 16B per lane; lds base must be wave-uniform
#define GLDS(src, dst)                                                   \
  __builtin_amdgcn_global_load_lds(                                      \
      (const __attribute__((address_space(1))) void*)(src),              \
      (__attribute__((address_space(3))) void*)(dst), 16, 0, 0)

#define FENCE asm volatile("" ::: "memory")
#define BAR()                         \
  do {                                \
    FENCE;                            \
    __builtin_amdgcn_s_barrier();     \
    FENCE;                            \
  } while (0)

// ---------------- embedding ----------------
__global__ __launch_bounds__(256) void embed_kernel(
    const int* __restrict__ x, const float* __restrict__ tok,
    const float* __restrict__ pos, float* __restrict__ h) {
  int row = blockIdx.x;
  int t = row & (SEQ - 1);
  int id = x[row];
  const float* tp = tok + (long)id * D_MODEL;
  const float* pp = pos + (long)t * D_MODEL;
  float* hp = h + (long)row * D_MODEL;
  for (int j = threadIdx.x; j < D_MODEL; j += 256)
    hp[j] = tp[j] + pp[j];
}

// ---------------- layernorm (f32 in) -> bf16 out ----------------
__global__ __launch_bounds__(256) void ln_kernel(
    const float* __restrict__ h, const float* __restrict__ sc,
    const float* __restrict__ sh, unsigned short* __restrict__ out) {
  __shared__ float red[4];
  int row = blockIdx.x;
  const float* x = h + (long)row * D_MODEL;
  int tid = threadIdx.x;
  float v0 = x[tid], v1 = x[tid + 256], v2 = x[tid + 512];
  float s = v0 + v1 + v2;
  for (int o = 32; o > 0; o >>= 1) s += __shfl_xor(s, o);
  if ((tid & 63) == 0) red[tid >> 6] = s;
  __syncthreads();
  float mean = (red[0] + red[1] + red[2] + red[3]) * (1.0f / D_MODEL);
  __syncthreads();
  float d0 = v0 - mean, d1 = v1 - mean, d2 = v2 - mean;
  float q = d0 * d0 + d1 * d1 + d2 * d2;
  for (int o = 32; o > 0; o >>= 1) q += __shfl_xor(q, o);
  if ((tid & 63) == 0) red[tid >> 6] = q;
  __syncthreads();
  float var = (red[0] + red[1] + red[2] + red[3]) * (1.0f / D_MODEL);
  float r = rsqrtf(var + 1e-5f);
  unsigned short* op = out + (long)row * D_MODEL;
  op[tid]       = f2bf(d0 * r * sc[tid]       + sh[tid]);
  op[tid + 256] = f2bf(d1 * r * sc[tid + 256] + sh[tid + 256]);
  op[tid + 512] = f2bf(d2 * r * sc[tid + 512] + sh[tid + 512]);
}

// ------- fused per-layer weight transpose -------
__global__ __launch_bounds__(256) void wtrans3_kernel(
    const float* __restrict__ qw, const float* __restrict__ fw,
    const float* __restrict__ pw, unsigned short* __restrict__ tq,
    unsigned short* __restrict__ tf, unsigned short* __restrict__ tp) {
  __shared__ unsigned short tile[32][33];
  int bid = blockIdx.x;
  const float* src; unsigned short* dst; int K, N, nb;
  if (bid < 1728)               { src = qw; dst = tq; K = 768;  N = 2304; nb = 72; }
  else if ((bid -= 1728) < 2304){ src = fw; dst = tf; K = 768;  N = 3072; nb = 96; }
  else { bid -= 2304;             src = pw; dst = tp; K = 3072; N = 768;  nb = 24; }
  int n0 = (bid % nb) * 32, k0 = (bid / nb) * 32;
  int tx = threadIdx.x & 31, ty = threadIdx.x >> 5;
  #pragma unroll
  for (int i = 0; i < 4; ++i) {
    int k = k0 + ty + i * 8;
    tile[ty + i * 8][tx] = f2bf(src[(long)k * N + n0 + tx]);
  }
  __syncthreads();
  #pragma unroll
  for (int i = 0; i < 4; ++i) {
    int nn = n0 + ty + i * 8;
    dst[(long)nn * K + k0 + tx] = tile[tx][ty + i * 8];
  }
}

// ---------------- head weight transpose (N tail) ----------------
__global__ __launch_bounds__(256) void wtrans_kernel(
    const float* __restrict__ w, unsigned short* __restrict__ wt, int K, int N) {
  __shared__ unsigned short tile[32][33];
  int n0 = blockIdx.x * 32, k0 = blockIdx.y * 32;
  int tx = threadIdx.x, ty = threadIdx.y;
  int n = n0 + tx; if (n >= N) n = N - 1;
  #pragma unroll
  for (int i = 0; i < 4; ++i) {
    int k = k0 + ty + i * 8;
    tile[ty + i * 8][tx] = f2bf(w[(long)k * N + n]);
  }
  __syncthreads();
  #pragma unroll
  for (int i = 0; i < 4; ++i) {
    int nn = n0 + ty + i * 8;
    if (nn < N) wt[(long)nn * K + k0 + tx] = tile[tx][ty + i * 8];
  }
}

// ---------------- V transpose: qkv bf16 -> vt[bh][DHEAD][SEQ] ----------------
__global__ __launch_bounds__(256) void vt_kernel(
    const unsigned short* __restrict__ qkv, unsigned short* __restrict__ vt) {
  __shared__ unsigned short tile[32][33];
  int bh = blockIdx.z, b = bh >> 2, hh = bh & 3;
  int t0 = blockIdx.x * 32, f0 = blockIdx.y * 32;
  int tx = threadIdx.x, ty = threadIdx.y;
  const unsigned short* src = qkv + (long)b * SEQ * 2304 + 2 * D_MODEL + hh * DHEAD;
  #pragma unroll
  for (int i = 0; i < 4; ++i) {
    int t = t0 + ty + i * 8;
    tile[ty + i * 8][tx] = src[(long)t * 2304 + f0 + tx];
  }
  __syncthreads();
  unsigned short* dst = vt + (long)bh * DHEAD * SEQ;
  #pragma unroll
  for (int i = 0; i < 4; ++i) {
    int f = f0 + ty + i * 8;
    dst[(long)f * SEQ + t0 + tx] = tile[tx][ty + i * 8];
  }
}

// ------- causal row softmax -------
__global__ __launch_bounds__(256) void softmax_kernel(
    const float* __restrict__ S, unsigned short* __restrict__ P) {
  __shared__ float red[4];
  long rid = blockIdx.x;
  int q = (int)(rid & (SEQ - 1));
  int tid = threadIdx.x;
  int i0 = tid * 4;
  f32x4 v;
  if (i0 <= q) {
    v = *(const f32x4*)(S + rid * SEQ + i0);
  } else {
    v = f32x4{-3.0e38f, -3.0e38f, -3.0e38f, -3.0e38f};
  }
  float m = -3.0e38f;
  #pragma unroll
  for (int j = 0; j < 4; ++j) {
    if (i0 + j > q) v[j] = -3.0e38f;
    m = fmaxf(m, v[j]);
  }
  for (int o = 32; o > 0; o >>= 1) m = fmaxf(m, __shfl_xor(m, o));
  if ((tid & 63) == 0) red[tid >> 6] = m;
  __syncthreads();
  m = fmaxf(fmaxf(red[0], red[1]), fmaxf(red[2], red[3]));
  __syncthreads();
  float e[4];
  float sum = 0.f;
  #pragma unroll
  for (int j = 0; j < 4; ++j) {
    e[j] = (i0 + j > q) ? 0.f : __expf(v[j] - m);
    sum += e[j];
  }
  for (int o = 32; o > 0; o >>= 1) sum += __shfl_xor(sum, o);
  if ((tid & 63) == 0) red[tid >> 6] = sum;
  __syncthreads();
  float inv = 1.0f / (red[0] + red[1] + red[2] + red[3]);
  if ((i0 >> 7) <= (q >> 7)) {
    u16x4 out;
    #pragma unroll
    for (int j = 0; j < 4; ++j) out[j] = f2bf(e[j] * inv);
    *(u16x4*)(P + rid * SEQ + i0) = out;
  }
}

// ======================= 256x256 8-phase GEMM =======================
// (R6-verified; used for QKV / FC / head)
template<int MODE>
__global__ __launch_bounds__(512, 2) void gemm256_kernel(
    const unsigned short* __restrict__ A,   // [M][K]
    const unsigned short* __restrict__ B,   // [N][K]
    const float* __restrict__ bias,
    void* __restrict__ Cv, int ldc,
    int M, int N, int K, int mb) {
  __shared__ __align__(16) unsigned short lds[2][2][2][128 * 64];

  int tid = threadIdx.x;
  int lane = tid & 63;
  int wid = tid >> 6;
  int wm = wid >> 2;
  int wn = wid & 3;

  int bid = blockIdx.x;
  int mpx = mb >> 3;
  int xcd = bid & 7;
  int c = bid >> 3;
  int m0 = (xcd * mpx + (c & (mpx - 1))) * 256;
  int n0 = (c / mpx) * 256;

  auto stageA = [&](int buf, int half, int kt) {
    const unsigned short* src = A + (long)(m0 + half * 128) * K + kt * 64;
    #pragma unroll
    for (int i = 0; i < 2; ++i) {
      int chunk = i * 8 + wid;
      int r = chunk * 8 + (lane >> 3);
      int cc = ((lane & 7) ^ (lane >> 3)) << 3;
      GLDS(src + (long)r * K + cc, &lds[buf][0][half][chunk * 512]);
    }
  };
  auto stageB = [&](int buf, int half, int kt) {
    #pragma unroll
    for (int i = 0; i < 2; ++i) {
      int chunk = i * 8 + wid;
      int r = chunk * 8 + (lane >> 3);
      int cc = ((lane & 7) ^ (lane >> 3)) << 3;
      int rg = n0 + half * 128 + r;
      if (rg >= N) rg = N - 1;
      GLDS(B + (long)rg * K + kt * 64 + cc, &lds[buf][1][half][chunk * 512]);
    }
  };

  auto lda_frag = [&](int buf, int f, int s) -> i32x4 {
    int r = wm * 64 + (f & 3) * 16 + (lane & 15);
    int kb = s * 64 + ((lane >> 4) << 4);
    int off = r * 128 + (kb ^ ((r & 7) << 4));
    return *(const i32x4*)((const char*)&lds[buf][0][f >> 2][0] + off);
  };
  auto ldb_frag = [&](int buf, int gg, int s) -> i32x4 {
    int r = wn * 32 + (gg & 1) * 16 + (lane & 15);
    int kb = s * 64 + ((lane >> 4) << 4);
    int off = r * 128 + (kb ^ ((r & 7) << 4));
    return *(const i32x4*)((const char*)&lds[buf][1][gg >> 1][0] + off);
  };

  f32x4 acc[8][4] = {};
  i32x4 a[4][2], b[4][2];

  int nt = K / 64;

  stageA(0, 0, 0); stageB(0, 0, 0); stageB(0, 1, 0); stageA(0, 1, 0);
  stageA(1, 0, 1); stageB(1, 0, 1); stageB(1, 1, 1);
  asm volatile("s_waitcnt vmcnt(6)" ::: "memory");
  BAR();

  for (int t = 0; t < nt; ++t) {
    int buf = t & 1, nbuf = buf ^ 1;
    #pragma unroll
    for (int fi = 0; fi < 4; ++fi) {
      a[fi][0] = lda_frag(buf, fi, 0);
      a[fi][1] = lda_frag(buf, fi, 1);
    }
    #pragma unroll
    for (int gi = 0; gi < 2; ++gi) {
      b[gi][0] = ldb_frag(buf, gi, 0);
      b[gi][1] = ldb_frag(buf, gi, 1);
    }
    if (t + 1 < nt) stageA(nbuf, 1, t + 1);
    BAR();
    __builtin_amdgcn_s_setprio(1);
    #pragma unroll
    for (int s = 0; s < 2; ++s)
      #pragma unroll
      for (int fi = 0; fi < 4; ++fi)
        #pragma unroll
        for (int gi = 0; gi < 2; ++gi)
          asm("v_mfma_f32_16x16x32_bf16 %0, %1, %2, %0"
              : "+v"(acc[fi][gi]) : "v"(b[gi][s]), "v"(a[fi][s]));
    __builtin_amdgcn_s_setprio(0);
    BAR();
    #pragma unroll
    for (int gi = 2; gi < 4; ++gi) {
      b[gi][0] = ldb_frag(buf, gi, 0);
      b[gi][1] = ldb_frag(buf, gi, 1);
    }
    if (t + 2 < nt) stageA(buf, 0, t + 2);
    BAR();
    __builtin_amdgcn_s_setprio(1);
    #pragma unroll
    for (int s = 0; s < 2; ++s)
      #pragma unroll
      for (int fi = 0; fi < 4; ++fi)
        #pragma unroll
        for (int gi = 2; gi < 4; ++gi)
          asm("v_mfma_f32_16x16x32_bf16 %0, %1, %2, %0"
              : "+v"(acc[fi][gi]) : "v"(b[gi][s]), "v"(a[fi][s]));
    __builtin_amdgcn_s_setprio(0);
    BAR();
    #pragma unroll
    for (int fi = 0; fi < 4; ++fi) {
      a[fi][0] = lda_frag(buf, 4 + fi, 0);
      a[fi][1] = lda_frag(buf, 4 + fi, 1);
    }
    if (t + 2 < nt) stageB(buf, 0, t + 2);
    BAR();
    __builtin_amdgcn_s_setprio(1);
    #pragma unroll
    for (int s = 0; s < 2; ++s)
      #pragma unroll
      for (int fi = 0; fi < 4; ++fi)
        #pragma unroll
        for (int gi = 2; gi < 4; ++gi)
          asm("v_mfma_f32_16x16x32_bf16 %0, %1, %2, %0"
              : "+v"(acc[4 + fi][gi]) : "v"(b[gi][s]), "v"(a[fi][s]));
    __builtin_amdgcn_s_setprio(0);
    BAR();
    if (t + 2 < nt) {
      stageB(buf, 1, t + 2);
      asm volatile("s_waitcnt vmcnt(6)" ::: "memory");
    } else if (t + 1 < nt) {
      asm volatile("s_waitcnt vmcnt(0)" ::: "memory");
    }
    BAR();
    __builtin_amdgcn_s_setprio(1);
    #pragma unroll
    for (int s = 0; s < 2; ++s)
      #pragma unroll
      for (int fi = 0; fi < 4; ++fi)
        #pragma unroll
        for (int gi = 0; gi < 2; ++gi)
          asm("v_mfma_f32_16x16x32_bf16 %0, %1, %2, %0"
              : "+v"(acc[4 + fi][gi]) : "v"(b[gi][s]), "v"(a[fi][s]));
    __builtin_amdgcn_s_setprio(0);
    BAR();
  }

  int cr = lane & 15;
  int cg = (lane >> 4) << 2;
  #pragma unroll
  for (int f = 0; f < 8; ++f) {
    long row = m0 + wm * 64 + (f & 3) * 16 + (f >> 2) * 128 + cr;
    #pragma unroll
    for (int gg = 0; gg < 4; ++gg) {
      int col = n0 + wn * 32 + (gg & 1) * 16 + (gg >> 1) * 128 + cg;
      f32x4 v = acc[f][gg];
      if (MODE == 0 || MODE == 1) {
        f32x4 bv = *(const f32x4*)(bias + col);
        u16x4 o;
        #pragma unroll
        for (int r = 0; r < 4; ++r) {
          float tt = v[r] + bv[r];
          if (MODE == 1) tt = fmaxf(tt, 0.f);
          o[r] = f2bf(tt);
        }
        *(u16x4*)((unsigned short*)Cv + row * (long)ldc + col) = o;
      } else {
        float* cp = (float*)Cv + row * (long)ldc + col;
        if (col + 4 <= N) {
          f32x4 bv = *(const f32x4*)(bias + col);
          f32x4 o;
          #pragma unroll
          for (int r = 0; r < 4; ++r) o[r] = v[r] + bv[r];
          *(f32x4*)cp = o;
        } else {
          #pragma unroll
          for (int r = 0; r < 4; ++r)
            if (col + r < N) cp[r] = v[r] + bias[col + r];
        }
      }
    }
  }
}

// ---------------- 128x128 GEMM (S / PV / PROJ) ----------------
#define BM 128
#define BN 128
#define BKK 32

template<int MODE>
__global__ __launch_bounds__(256) void gemm_kernel(
    const unsigned short* __restrict__ A, int lda,
    const unsigned short* __restrict__ B, int ldb,
    const float* __restrict__ bias,
    void* __restrict__ Cv, int ldc,
    int M, int N, int K,
    int NI, long sAo, long sAi, long sBo, long sBi,
    long sCo, long sCi, float alpha, int causal, int mblocks) {
  __shared__ __align__(16) unsigned short As[2][BM * BKK];
  __shared__ __align__(16) unsigned short Bs[2][BN * BKK];
  int z = blockIdx.z;
  int zo = z / NI, zi = z - zo * NI;
  A += zo * sAo + zi * sAi;
  B += zo * sBo + zi * sBi;
  long coff = zo * sCo + zi * sCi;

  int m0, n0;
  if (mblocks > 0) {
    int bid = blockIdx.x;
    int mpx = mblocks >> 3;
    int xcd = bid & 7;
    int c = bid >> 3;
    m0 = (xcd * mpx + (c & (mpx - 1))) * BM;
    n0 = (c / mpx) * BN;
  } else {
    m0 = blockIdx.y * BM;
    n0 = blockIdx.x * BN;
  }
  if (causal == 1 && n0 > m0 + BM - 1) return;
  int kmax = (causal == 2) ? min(K, m0 + BM) : K;

  int tid = threadIdx.x;
  int lane = tid & 63;
  int wave = tid >> 6;
  int wm = (wave >> 1) * 64;
  int wn = (wave & 1) * 64;

  auto stage = [&](int buf, int k0) {
    #pragma unroll
    for (int i = 0; i < 2; ++i) {
      int c0 = i * 256 + wave * 64;
      int cc = c0 + lane;
      int row = cc >> 2;
      int ko = (cc & 3) << 3;
      GLDS(A + (long)(m0 + row) * lda + k0 + ko, As[buf] + c0 * 8);
      int rg = n0 + row; if (rg >= N) rg = N - 1;
      GLDS(B + (long)rg * ldb + k0 + ko, Bs[buf] + c0 * 8);
    }
  };

  f32x4 acc[4][4] = {};
  int nt = kmax / BKK;
  stage(0, 0);
  __syncthreads();
  int cur = 0;
  for (int t = 0; t < nt; ++t) {
    if (t + 1 < nt) stage(cur ^ 1, (t + 1) * BKK);
    int lr = lane & 15;
    int kg = (lane >> 4) << 3;
    i32x4 af[4], bf[4];
    #pragma unroll
    for (int mi = 0; mi < 4; ++mi)
      af[mi] = *(const i32x4*)(As[cur] + (wm + mi * 16 + lr) * BKK + kg);
    #pragma unroll
    for (int ni = 0; ni < 4; ++ni)
      bf[ni] = *(const i32x4*)(Bs[cur] + (wn + ni * 16 + lr) * BKK + kg);
    #pragma unroll
    for (int mi = 0; mi < 4; ++mi)
      #pragma unroll
      for (int ni = 0; ni < 4; ++ni)
        asm("v_mfma_f32_16x16x32_bf16 %0, %1, %2, %0"
            : "+v"(acc[mi][ni]) : "v"(bf[ni]), "v"(af[mi]));
    __syncthreads();
    cur ^= 1;
  }

  int cm = lane & 15;
  int cg = (lane >> 4) << 2;
  #pragma unroll
  for (int mi = 0; mi < 4; ++mi) {
    long row = m0 + wm + mi * 16 + cm;
    #pragma unroll
    for (int ni = 0; ni < 4; ++ni) {
      int col = n0 + wn + ni * 16 + cg;
      f32x4 v = acc[mi][ni];
      if (MODE == 2) {
        #pragma unroll
        for (int r = 0; r < 4; ++r) v[r] *= alpha;
        *(f32x4*)((float*)Cv + coff + row * (long)ldc + col) = v;
      } else if (MODE == 0 || MODE == 1) {
        f32x4 bv = *(const f32x4*)(bias + col);
        u16x4 o;
        #pragma unroll
        for (int r = 0; r < 4; ++r) {
          float t = v[r] + bv[r];
          if (MODE == 1) t = fmaxf(t, 0.f);
          o[r] = f2bf(t);
        }
        *(u16x4*)((unsigned short*)Cv + coff + row * (long)ldc + col) = o;
      } else {
        float* cp = (float*)Cv + coff + row * (long)ldc + col;
        if (col + 4 <= N) {
          f32x4 bv = bias ? *(const f32x4*)(bias + col)
                          : f32x4{0.f, 0.f, 0.f, 0.f};
          if (MODE == 3) {
            f32x4 old = *(f32x4*)cp;
            #pragma unroll
            for (int r = 0; r < 4; ++r) old[r] += v[r] + bv[r];
            *(f32x4*)cp = old;
          } else {
            f32x4 o;
            #pragma unroll
            for (int r = 0; r < 4; ++r) o[r] = v[r] + bv[r];
            *(f32x4*)cp = o;
          }
        } else {
          #pragma unroll
          for (int r = 0; r < 4; ++r) {
            if (col + r < N) {
              float bvr = bias ? bias[col + r] : 0.f;
              if (MODE == 3) cp[r] += v[r] + bvr;
              else           cp[r] = v[r] + bvr;
            }
          }
        }
      }
    }
  }
}

extern "C" void kernel_launch(void* const* d_in, const int* in_sizes, int n_in,
                              void* d_out, int out_size, void* d_ws, size_t ws_size,
                              hipStream_t stream) {
  const int*   x       = (const int*)  d_in[0];
  const float* tok_emb = (const float*)d_in[1];
  const float* pos_emb = (const float*)d_in[2];
  const float* ln1_s   = (const float*)d_in[3];
  const float* ln1_b   = (const float*)d_in[4];
  const float* qkv_w   = (const float*)d_in[5];
  const float* qkv_b   = (const float*)d_in[6];
  const float* ln2_s   = (const float*)d_in[7];
  const float* ln2_b   = (const float*)d_in[8];
  const float* fc_w    = (const float*)d_in[9];
  const float* fc_b    = (const float*)d_in[10];
  const float* proj_w  = (const float*)d_in[11];
  const float* proj_b  = (const float*)d_in[12];
  const float* lnf_s   = (const float*)d_in[13];
  const float* lnf_b   = (const float*)d_in[14];
  const float* head_w  = (const float*)d_in[15];
  const float* head_b  = (const float*)d_in[16];

  char* ws = (char*)d_ws;
  size_t off = 0;
  auto alloc = [&](size_t bytes) {
    char* p = ws + off;
    off += (bytes + 255) & ~(size_t)255;
    return p;
  };
  float*          h   = (float*)         alloc((size_t)NTOK * D_MODEL * 4);
  unsigned short* lnb = (unsigned short*)alloc((size_t)NTOK * D_MODEL * 2);
  unsigned short* qkv = (unsigned short*)alloc((size_t)NTOK * 2304 * 2);
  unsigned short* vt  = (unsigned short*)alloc((size_t)16 * DHEAD * SEQ * 2);
  unsigned short* mid = (unsigned short*)alloc((size_t)NTOK * 3072 * 2);
  float*          S   = (float*)         alloc((size_t)16 * SEQ * SEQ * 4);
  unsigned short* P   = (unsigned short*)alloc((size_t)16 * SEQ * SEQ * 2);
  unsigned short* wtq = (unsigned short*)alloc((size_t)2304 * 768 * 2);
  unsigned short* wtf = (unsigned short*)alloc((size_t)3072 * 768 * 2);
  unsigned short* wtp = (unsigned short*)alloc((size_t)768 * 3072 * 2);
  unsigned short* wth = (unsigned short*)alloc((size_t)50304 * 768 * 2);

  embed_kernel<<<NTOK, 256, 0, stream>>>(x, tok_emb, pos_emb, h);

  const float rscale = 0.07216878364870323f;  // 1/sqrt(192)

  for (int l = 0; l < NLAYER; ++l) {
    wtrans3_kernel<<<6336, 256, 0, stream>>>(
        qkv_w + (long)l * 768 * 2304, fc_w + (long)l * 768 * 3072,
        proj_w + (long)l * 3072 * 768, wtq, wtf, wtp);
    // ---- attention ----
    ln_kernel<<<NTOK, 256, 0, stream>>>(h, ln1_s + l * 768, ln1_b + l * 768, lnb);
    gemm256_kernel<0><<<16 * 9, 512, 0, stream>>>(
        lnb, wtq, qkv_b + l * 2304, qkv, 2304, 4096, 2304, 768, 16);
    vt_kernel<<<dim3(32, 6, 16), dim3(32, 8), 0, stream>>>(qkv, vt);
    gemm_kernel<2><<<dim3(8, 8, 16), 256, 0, stream>>>(
        qkv, 2304, qkv + 768, 2304, nullptr, S, 1024,
        1024, 1024, 192, 4,
        (long)1024 * 2304, 192, (long)1024 * 2304, 192,
        (long)4 * 1024 * 1024, (long)1024 * 1024, rscale, 1, 0);
    softmax_kernel<<<16384, 256, 0, stream>>>(S, P);
    gemm_kernel<3><<<dim3(2, 8, 16), 256, 0, stream>>>(
        P, 1024, vt, 1024, nullptr, h, 768,
        1024, 192, 1024, 4,
        (long)4 * 1024 * 1024, (long)1024 * 1024,
        (long)4 * 192 * 1024, (long)192 * 1024,
        (long)1024 * 768, 192, 1.0f, 2, 0);
    // ---- MLP ----
    ln_kernel<<<NTOK, 256, 0, stream>>>(h, ln2_s + l * 768, ln2_b + l * 768, lnb);
    gemm256_kernel<1><<<16 * 12, 512, 0, stream>>>(
        lnb, wtf, fc_b + l * 3072, mid, 3072, 4096, 3072, 768, 16);
    // PROJ: 1D grid, m-chunk-per-XCD swizzle (bijective: 8 xcd x 4 m x 6 n)
    gemm_kernel<3><<<192, 256, 0, stream>>>(
        mid, 3072, wtp, 3072, proj_b + l * 768, h, 768,
        4096, 768, 3072, 1, 0, 0, 0, 0, 0, 0, 1.0f, 0, 32);
  }

  // ---- final LN + head ----
  wtrans_kernel<<<dim3(1571, 24), dim3(32, 8), 0, stream>>>(head_w, wth, 768, 50257);
  ln_kernel<<<NTOK, 256, 0, stream>>>(h, lnf_s, lnf_b, lnb);
  gemm256_kernel<4><<<16 * 197, 512, 0, stream>>>(
      lnb, wth, head_b, (float*)d_out, 50257, 4096, 50257, 768, 16);
}